// Round 3
// baseline (426.305 us; speedup 1.0000x reference)
//
#include <hip/hip_runtime.h>

#define N_NODES 50000
#define N_EDGES 800000
#define DIN     128
#define H       96
#define K_EXP   8
#define L_LAYERS 4
#define C_OUT   40

#define GSZ 6250   // rows per XCD group = N_NODES/8

typedef _Float16 f16;
typedef f16 f16x2 __attribute__((ext_vector_type(2)));
typedef f16 f16x4 __attribute__((ext_vector_type(4)));
typedef f16 f16x8 __attribute__((ext_vector_type(8)));
typedef float f32x4 __attribute__((ext_vector_type(4)));

// ---------------- CSR build + weight conversion (merged) ----------------

#define CONV_TOT (L_LAYERS * K_EXP * H * H)   // 294912
#define FC0_TOT  (DIN * H)                    // 12288
#define FC1_TOT  (48 * H)                     // 4608
#define CNT_BLOCKS ((N_EDGES + 255) / 256)            // 3125
#define CVT_BLOCKS ((CONV_TOT + FC0_TOT + FC1_TOT + 255) / 256)  // 1218

__global__ __launch_bounds__(256) void count_convert(const int* __restrict__ row,
                                                     int* __restrict__ deg,
                                                     int* __restrict__ p,
                                                     const float* __restrict__ conv_w,
                                                     const float* __restrict__ fc0_w,
                                                     const float* __restrict__ fc1_w,
                                                     f16* __restrict__ wfrag,
                                                     f16* __restrict__ fc0t,
                                                     f16* __restrict__ fc1t) {
    int tid = threadIdx.x;
    if ((int)blockIdx.x < CNT_BLOCKS) {
        int i = blockIdx.x * 256 + tid;
        if (i < N_EDGES) p[i] = atomicAdd(&deg[row[i]], 1);
    } else {
        int i = ((int)blockIdx.x - CNT_BLOCKS) * 256 + tid;
        if (i < CONV_TOT) {
            int o = i % H;
            int t = i / H;
            int d = t % H;
            int lk = t / H;
            int ct = o >> 4, lc = o & 15;
            int ks = d >> 5, quad = (d >> 3) & 3, j = d & 7;
            wfrag[(size_t)lk * 9216 + ct * 1536 + ks * 512 + (quad * 16 + lc) * 8 + j] =
                (f16)conv_w[i];
        } else if (i < CONV_TOT + FC0_TOT) {
            int j = i - CONV_TOT;      // j = d*96+o
            int o = j % H, d = j / H;
            fc0t[o * DIN + d] = (f16)fc0_w[j];
        } else if (i < CONV_TOT + FC0_TOT + FC1_TOT) {
            int j = i - CONV_TOT - FC0_TOT;  // target [o][d]
            int o = j / H, d = j % H;
            fc1t[j] = (o < C_OUT) ? (f16)fc1_w[d * C_OUT + o] : (f16)0.f;
        }
    }
}

__global__ __launch_bounds__(1024) void scanA(const int* __restrict__ deg,
                                              int* __restrict__ rowptr,
                                              int* __restrict__ partial, int n) {
    __shared__ int wsum[16];
    int tid  = threadIdx.x;
    int lane = tid & 63, wid = tid >> 6;
    int idx = blockIdx.x * 1024 + tid;
    int v = (idx < n) ? deg[idx] : 0;
    int s = v;
    #pragma unroll
    for (int off = 1; off < 64; off <<= 1) {
        int t = __shfl_up(s, off, 64);
        if (lane >= off) s += t;
    }
    if (lane == 63) wsum[wid] = s;
    __syncthreads();
    if (wid == 0 && lane < 16) {
        int w = wsum[lane];
        #pragma unroll
        for (int off = 1; off < 16; off <<= 1) {
            int t = __shfl_up(w, off, 16);
            if (lane >= off) w += t;
        }
        wsum[lane] = w;
    }
    __syncthreads();
    int waveoff = (wid == 0) ? 0 : wsum[wid - 1];
    if (idx < n) rowptr[idx + 1] = waveoff + s;
    if (tid == 1023) partial[blockIdx.x] = waveoff + s;
}

__global__ __launch_bounds__(1024) void scanC(int* __restrict__ rowptr,
                                              const int* __restrict__ partial,
                                              int nb, int n) {
    __shared__ int boff_s;
    int tid = threadIdx.x;
    if (tid < 64) {
        int v = 0;
        for (int j = tid; j < (int)blockIdx.x; j += 64) v += partial[j];
        #pragma unroll
        for (int off = 32; off >= 1; off >>= 1) v += __shfl_xor(v, off, 64);
        if (tid == 0) boff_s = v;
    }
    __syncthreads();
    int boff = boff_s;
    int idx = blockIdx.x * 1024 + tid;
    if (idx == 0) rowptr[0] = 0;
    if (idx < n) rowptr[idx + 1] += boff;
}

__global__ __launch_bounds__(256) void scatter_store_xcd(const int* __restrict__ row,
                                                         const int* __restrict__ col,
                                                         const int* __restrict__ p,
                                                         const int* __restrict__ rowptr,
                                                         int* __restrict__ csr, int e) {
    int g = blockIdx.x & 7;
    int rlo = g * GSZ, rhi = rlo + GSZ;
    int stride = (gridDim.x >> 3) * 256;
    for (int i = (blockIdx.x >> 3) * 256 + threadIdx.x; i < e; i += stride) {
        int r = row[i];
        if (r >= rlo && r < rhi)
            csr[rowptr[r] + p[i]] = col[i];
    }
}

// ---------------- fused per-layer pre-pass: spmm + ctx softmax ----------------
// spmm: ONE ROW PER WAVE. The row's CSR indices are wave-uniform: loaded once
// (lane<deg), extracted via v_readlane (no LDS shuffle on the critical path).
// Each load instruction gathers 4 edges (lanes 0-11 -> edge t, 16-27 -> t+1,
// 32-43 -> t+2, 48-59 -> t+3; 12 lanes x 16B = one 192B row each). Inner loop
// hand-pipelined x2 (8 edges, 2 loads in flight). Cross-quarter shfl_xor
// reduce once per row. 50000 waves -> full occupancy, deep MLP.

#define SPMM_WPB 4
#define SPMM_BLOCKS ((N_NODES + SPMM_WPB - 1) / SPMM_WPB)   // 12500
#define CTX_BLOCKS  ((N_NODES + 255) / 256)                 // 196

__global__ __launch_bounds__(256) void layer_pre(const f16* __restrict__ h16,
                                                 const int* __restrict__ rowptr,
                                                 const int* __restrict__ csr,
                                                 f16* __restrict__ hi16,
                                                 const float* __restrict__ cw,
                                                 const float* __restrict__ cb,
                                                 float* __restrict__ zt, int n) {
    __shared__ float ws[H * K_EXP];
    __shared__ float bs[K_EXP];
    int tid = threadIdx.x;
    if ((int)blockIdx.x < SPMM_BLOCKS) {
        int wid  = tid >> 6;
        int lane = tid & 63;
        int r = blockIdx.x * SPMM_WPB + wid;
        if (r >= n) return;
        int q16 = lane >> 4;          // which edge of the quad this lane serves
        int li  = lane & 15;          // 16B slice within the row
        bool act_l = li < 12;         // rows are 12 x 16B = 192B
        int j = rowptr[r], e = rowptr[r + 1];
        float acc[8] = {};
        const size_t lane_off = (size_t)li * 8;
        for (int jb = j; jb < e; jb += 64) {
            int m = e - jb; if (m > 64) m = 64;
            int c = 0;
            if (lane < m) c = csr[jb + lane];
            for (int t = 0; t < m; t += 8) {
                // quad A: edges t .. t+3
                int a0 = __builtin_amdgcn_readlane(c, t);
                int a1 = __builtin_amdgcn_readlane(c, t + 1);
                int a2 = __builtin_amdgcn_readlane(c, t + 2);
                int a3 = __builtin_amdgcn_readlane(c, t + 3);
                int ca = q16 == 0 ? a0 : q16 == 1 ? a1 : q16 == 2 ? a2 : a3;
                bool actA = act_l && (t + q16 < m);
                f16x8 vA = {};
                if (actA) vA = *(const f16x8*)(h16 + (size_t)ca * H + lane_off);
                // quad B: edges t+4 .. t+7 (issued before consuming A)
                int b0 = __builtin_amdgcn_readlane(c, t + 4);
                int b1 = __builtin_amdgcn_readlane(c, t + 5);
                int b2 = __builtin_amdgcn_readlane(c, t + 6);
                int b3 = __builtin_amdgcn_readlane(c, t + 7);
                int cbx = q16 == 0 ? b0 : q16 == 1 ? b1 : q16 == 2 ? b2 : b3;
                bool actB = act_l && (t + 4 + q16 < m);
                f16x8 vB = {};
                if (actB) vB = *(const f16x8*)(h16 + (size_t)cbx * H + lane_off);
                if (actA) {
                    #pragma unroll
                    for (int q = 0; q < 8; q++) acc[q] += (float)vA[q];
                }
                if (actB) {
                    #pragma unroll
                    for (int q = 0; q < 8; q++) acc[q] += (float)vB[q];
                }
            }
        }
        // combine the 4 lane-quarters (each holds a partial over its edges)
        #pragma unroll
        for (int q = 0; q < 8; q++) {
            acc[q] += __shfl_xor(acc[q], 32, 64);
            acc[q] += __shfl_xor(acc[q], 16, 64);
        }
        if (lane < 12) {
            f16x8 o;
            #pragma unroll
            for (int q = 0; q < 8; q++) o[q] = (f16)acc[q];
            *(f16x8*)(hi16 + (size_t)r * H + lane * 8) = o;
        }
    } else {
        for (int t = tid; t < H * K_EXP; t += 256) ws[t] = cw[t];
        if (tid < K_EXP) bs[tid] = cb[tid];
        __syncthreads();
        int node = ((int)blockIdx.x - SPMM_BLOCKS) * 256 + tid;
        if (node >= n) return;
        float acc[K_EXP];
        #pragma unroll
        for (int k = 0; k < K_EXP; k++) acc[k] = bs[k];
        const f16* hr = h16 + (size_t)node * H;
        #pragma unroll 3
        for (int c8 = 0; c8 < 12; c8++) {
            f16x8 v = *(const f16x8*)(hr + c8 * 8);
            #pragma unroll
            for (int j = 0; j < 8; j++) {
                float hv = (float)v[j];
                int d = c8 * 8 + j;
                #pragma unroll
                for (int k = 0; k < K_EXP; k++) acc[k] += hv * ws[d * K_EXP + k];
            }
        }
        float mx = acc[0];
        #pragma unroll
        for (int k = 1; k < K_EXP; k++) mx = fmaxf(mx, acc[k]);
        float s = 0.f;
        #pragma unroll
        for (int k = 0; k < K_EXP; k++) { acc[k] = __expf(acc[k] - mx); s += acc[k]; }
        float inv = 1.f / s;
        #pragma unroll
        for (int k = 0; k < K_EXP; k++)
            zt[(size_t)k * N_NODES + node] = acc[k] * inv;
    }
}

// ---------------- fc0 via fp16 MFMA (writes fp16 h only) ----------------

#define FPAD 136

__global__ __launch_bounds__(256) void fc0_kernel(const float* __restrict__ x,
                                                  const f16* __restrict__ fc0t,
                                                  const float* __restrict__ b,
                                                  f16* __restrict__ h16, int n) {
    __shared__ f16 As[64 * FPAD];
    __shared__ f16 Ws[96 * FPAD];
    int tid = threadIdx.x;
    int l = tid & 63, w = tid >> 6;
    int quad = l >> 4, lc = l & 15;
    int row0 = blockIdx.x * 64;

    for (int t = tid; t < 2048; t += 256) {
        int m = t >> 5, c4 = (t & 31) * 4;
        int gr = row0 + m;
        float4 v = {0.f, 0.f, 0.f, 0.f};
        if (gr < n) v = *(const float4*)(x + (size_t)gr * DIN + c4);
        f16x4 h4 = {(f16)v.x, (f16)v.y, (f16)v.z, (f16)v.w};
        *(f16x4*)&As[m * FPAD + c4] = h4;
    }
    for (int t = tid; t < 1536; t += 256) {
        int o = t >> 4, c8 = (t & 15) * 8;
        *(f16x8*)&Ws[o * FPAD + c8] = *(const f16x8*)(fc0t + o * DIN + c8);
    }
    __syncthreads();

    f16x8 afr[4];
    #pragma unroll
    for (int ks = 0; ks < 4; ks++)
        afr[ks] = *(const f16x8*)&As[(16 * w + lc) * FPAD + ks * 32 + quad * 8];

    f32x4 acc[6] = {};
    #pragma unroll
    for (int ct = 0; ct < 6; ct++) {
        #pragma unroll
        for (int ks = 0; ks < 4; ks++) {
            f16x8 bfr = *(const f16x8*)&Ws[(ct * 16 + lc) * FPAD + ks * 32 + quad * 8];
            acc[ct] = __builtin_amdgcn_mfma_f32_16x16x32_f16(afr[ks], bfr, acc[ct], 0, 0, 0);
        }
    }

    int m0 = 16 * w + quad * 4;
    #pragma unroll
    for (int r = 0; r < 4; r++) {
        int gr = row0 + m0 + r;
        if (gr < n) {
            #pragma unroll
            for (int ct = 0; ct < 6; ct++) {
                int o = ct * 16 + lc;
                h16[(size_t)gr * H + o] = (f16)fmaxf(acc[ct][r] + b[o], 0.f);
            }
        }
    }
}

// ---------------- expert GEMM: 128 rows/block, LDS-staged fragment weights ----------------

#define EG_STAGE 2
#define EG_HALFS (EG_STAGE * 9216)   // 18432 halfs = 36 KB

__global__ __launch_bounds__(256) void expert_gemm(const f16* __restrict__ hi16,
                                                   const f16* __restrict__ hin16,
                                                   const f16* __restrict__ wfrag, // [K][9216]
                                                   const float* __restrict__ zt,  // [K][N]
                                                   f16* __restrict__ hout16, int n) {
    __shared__ f16 Wl[EG_HALFS];
    int tid = threadIdx.x;
    int l = tid & 63, w = tid >> 6;
    int quad = l >> 4, lc = l & 15;
    int brow = blockIdx.x * 128;
    int wrow0 = brow + w * 16;          // M-tile 0 for this wave
    int wrow1 = wrow0 + 64;             // M-tile 1

    f16x8 afr0[3], afr1[3];
    #pragma unroll
    for (int ks = 0; ks < 3; ks++) {
        afr0[ks] = *(const f16x8*)(hi16 + (size_t)(wrow0 + lc) * H + ks * 32 + quad * 8);
        afr1[ks] = *(const f16x8*)(hi16 + (size_t)(wrow1 + lc) * H + ks * 32 + quad * 8);
    }

    f32x4 acc0[6] = {};
    f32x4 acc1[6] = {};

    for (int kb = 0; kb < K_EXP; kb += EG_STAGE) {
        __syncthreads();
        const f16* src = wfrag + (size_t)kb * 9216;
        for (int t = tid; t < EG_HALFS / 8; t += 256)
            *(f16x8*)&Wl[t * 8] = *(const f16x8*)(src + t * 8);
        __syncthreads();

        #pragma unroll
        for (int k2 = 0; k2 < EG_STAGE; k2++) {
            int k = kb + k2;
            f32x4 zf0 = *(const f32x4*)(zt + (size_t)k * N_NODES + wrow0 + quad * 4);
            f32x4 zf1 = *(const f32x4*)(zt + (size_t)k * N_NODES + wrow1 + quad * 4);
            #pragma unroll
            for (int ct = 0; ct < 6; ct++) {
                f16x8 b0 = *(const f16x8*)&Wl[k2 * 9216 + ct * 1536 + 0 * 512 + l * 8];
                f16x8 b1 = *(const f16x8*)&Wl[k2 * 9216 + ct * 1536 + 1 * 512 + l * 8];
                f16x8 b2 = *(const f16x8*)&Wl[k2 * 9216 + ct * 1536 + 2 * 512 + l * 8];
                f32x4 t0 = {};
                t0 = __builtin_amdgcn_mfma_f32_16x16x32_f16(afr0[0], b0, t0, 0, 0, 0);
                t0 = __builtin_amdgcn_mfma_f32_16x16x32_f16(afr0[1], b1, t0, 0, 0, 0);
                t0 = __builtin_amdgcn_mfma_f32_16x16x32_f16(afr0[2], b2, t0, 0, 0, 0);
                acc0[ct] += zf0 * t0;
                f32x4 t1 = {};
                t1 = __builtin_amdgcn_mfma_f32_16x16x32_f16(afr1[0], b0, t1, 0, 0, 0);
                t1 = __builtin_amdgcn_mfma_f32_16x16x32_f16(afr1[1], b1, t1, 0, 0, 0);
                t1 = __builtin_amdgcn_mfma_f32_16x16x32_f16(afr1[2], b2, t1, 0, 0, 0);
                acc1[ct] += zf1 * t1;
            }
        }
    }

    #pragma unroll
    for (int r = 0; r < 4; r++) {
        int gr0 = wrow0 + quad * 4 + r;
        if (gr0 < n) {
            #pragma unroll
            for (int ct = 0; ct < 6; ct++) {
                int o = ct * 16 + lc;
                float v = fmaxf(acc0[ct][r] + (float)hin16[(size_t)gr0 * H + o], 0.f);
                hout16[(size_t)gr0 * H + o] = (f16)v;
            }
        }
        int gr1 = wrow1 + quad * 4 + r;
        if (gr1 < n) {
            #pragma unroll
            for (int ct = 0; ct < 6; ct++) {
                int o = ct * 16 + lc;
                float v = fmaxf(acc1[ct][r] + (float)hin16[(size_t)gr1 * H + o], 0.f);
                hout16[(size_t)gr1 * H + o] = (f16)v;
            }
        }
    }
}

// ---------------- fc1 via fp16 MFMA ----------------

#define APAD 104

__global__ __launch_bounds__(256) void fc1_kernel(const f16* __restrict__ h16,
                                                  const f16* __restrict__ fc1t,
                                                  const float* __restrict__ b,
                                                  float* __restrict__ out, int n) {
    __shared__ f16 As[64 * APAD];
    __shared__ f16 Ws[48 * APAD];
    int tid = threadIdx.x;
    int l = tid & 63, w = tid >> 6;
    int quad = l >> 4, lc = l & 15;
    int row0 = blockIdx.x * 64;

    for (int t = tid; t < 768; t += 256) {
        int m = t / 12, c8 = (t % 12) * 8;
        int gr = row0 + m;
        f16x8 v = {};
        if (gr < n) v = *(const f16x8*)(h16 + (size_t)gr * H + c8);
        *(f16x8*)&As[m * APAD + c8] = v;
    }
    for (int t = tid; t < 576; t += 256) {
        int o = t / 12, c8 = (t % 12) * 8;
        *(f16x8*)&Ws[o * APAD + c8] = *(const f16x8*)(fc1t + o * H + c8);
    }
    __syncthreads();

    f16x8 afr[3];
    #pragma unroll
    for (int ks = 0; ks < 3; ks++)
        afr[ks] = *(const f16x8*)&As[(16 * w + lc) * APAD + ks * 32 + quad * 8];

    f32x4 acc[3] = {};
    #pragma unroll
    for (int ct = 0; ct < 3; ct++) {
        #pragma unroll
        for (int ks = 0; ks < 3; ks++) {
            f16x8 bfr = *(const f16x8*)&Ws[(ct * 16 + lc) * APAD + ks * 32 + quad * 8];
            acc[ct] = __builtin_amdgcn_mfma_f32_16x16x32_f16(afr[ks], bfr, acc[ct], 0, 0, 0);
        }
    }

    int m0 = 16 * w + quad * 4;
    #pragma unroll
    for (int r = 0; r < 4; r++) {
        int gr = row0 + m0 + r;
        if (gr < n) {
            #pragma unroll
            for (int ct = 0; ct < 3; ct++) {
                int o = ct * 16 + lc;
                if (o < C_OUT)
                    out[(size_t)gr * C_OUT + o] = acc[ct][r] + b[o];
            }
        }
    }
}

// ---------------- launch ----------------

extern "C" void kernel_launch(void* const* d_in, const int* in_sizes, int n_in,
                              void* d_out, int out_size, void* d_ws, size_t ws_size,
                              hipStream_t stream) {
    const float* x      = (const float*)d_in[0];
    const int*   ei     = (const int*)d_in[1];
    const float* fc0_w  = (const float*)d_in[2];
    const float* fc0_b  = (const float*)d_in[3];
    const float* fc1_w  = (const float*)d_in[4];
    const float* fc1_b  = (const float*)d_in[5];
    const float* ctx_w  = (const float*)d_in[6];
    const float* ctx_b  = (const float*)d_in[7];
    const float* conv_w = (const float*)d_in[8];
    float* out = (float*)d_out;

    const size_t NH = (size_t)N_NODES * H;

    float* zbuf = (float*)d_ws;                          // [K][N] transposed
    f16*   h16a = (f16*)(zbuf + (size_t)N_NODES * K_EXP);
    f16*   h16b = h16a + NH;
    f16*   hi16 = h16b + NH;
    f16*   wfrag= hi16 + NH;
    f16*   fc0t = wfrag + CONV_TOT;
    f16*   fc1t = fc0t + FC0_TOT;
    int* rowptr = (int*)(fc1t + FC1_TOT);                // N+1
    int* deg    = rowptr + (N_NODES + 1);                // N
    int* csr    = deg + N_NODES;                         // E
    int* prank  = csr + N_EDGES;                         // E
    int* partial  = prank + N_EDGES;                     // 64

    const int* row = ei;
    const int* col = ei + N_EDGES;

    hipMemsetAsync(deg, 0, sizeof(int) * N_NODES, stream);

    count_convert<<<CNT_BLOCKS + CVT_BLOCKS, 256, 0, stream>>>(
        row, deg, prank, conv_w, fc0_w, fc1_w, wfrag, fc0t, fc1t);
    int nsb = (N_NODES + 1023) / 1024;   // 49
    scanA<<<nsb, 1024, 0, stream>>>(deg, rowptr, partial, N_NODES);
    scanC<<<nsb, 1024, 0, stream>>>(rowptr, partial, nsb, N_NODES);
    scatter_store_xcd<<<1024, 256, 0, stream>>>(row, col, prank, rowptr, csr, N_EDGES);

    int gemm_grid = (N_NODES + 63) / 64;   // 782
    fc0_kernel<<<gemm_grid, 256, 0, stream>>>(x, fc0t, fc0_b, h16a, N_NODES);

    int eg_grid = (N_NODES + 127) / 128;   // 391
    f16* hcur = h16a;
    f16* hnext = h16b;
    for (int i = 0; i < L_LAYERS; i++) {
        layer_pre<<<SPMM_BLOCKS + CTX_BLOCKS, 256, 0, stream>>>(
            hcur, rowptr, csr, hi16,
            ctx_w + (size_t)i * H * K_EXP, ctx_b + (size_t)i * K_EXP, zbuf, N_NODES);
        expert_gemm<<<eg_grid, 256, 0, stream>>>(
            hi16, hcur, wfrag + (size_t)i * K_EXP * H * H, zbuf, hnext, N_NODES);
        f16* t = hcur; hcur = hnext; hnext = t;
    }
    fc1_kernel<<<gemm_grid, 256, 0, stream>>>(hcur, fc1t, fc1_b, out, N_NODES);
}

// Round 4
// 384.033 us; speedup vs baseline: 1.1101x; 1.1101x over previous
//
#include <hip/hip_runtime.h>

#define N_NODES 50000
#define N_EDGES 800000
#define DIN     128
#define H       96
#define K_EXP   8
#define L_LAYERS 4
#define C_OUT   40

#define GSZ 6250   // rows per XCD group = N_NODES/8

typedef _Float16 f16;
typedef f16 f16x2 __attribute__((ext_vector_type(2)));
typedef f16 f16x4 __attribute__((ext_vector_type(4)));
typedef f16 f16x8 __attribute__((ext_vector_type(8)));
typedef float f32x4 __attribute__((ext_vector_type(4)));

// ---------------- CSR build + weight conversion (merged) ----------------

#define CONV_TOT (L_LAYERS * K_EXP * H * H)   // 294912
#define FC0_TOT  (DIN * H)                    // 12288
#define FC1_TOT  (48 * H)                    // 4608
#define CNT_BLOCKS ((N_EDGES + 255) / 256)            // 3125
#define CVT_BLOCKS ((CONV_TOT + FC0_TOT + FC1_TOT + 255) / 256)  // 1218

__global__ __launch_bounds__(256) void count_convert(const int* __restrict__ row,
                                                     int* __restrict__ deg,
                                                     int* __restrict__ p,
                                                     const float* __restrict__ conv_w,
                                                     const float* __restrict__ fc0_w,
                                                     const float* __restrict__ fc1_w,
                                                     f16* __restrict__ wfrag,
                                                     f16* __restrict__ fc0t,
                                                     f16* __restrict__ fc1t) {
    int tid = threadIdx.x;
    if ((int)blockIdx.x < CNT_BLOCKS) {
        int i = blockIdx.x * 256 + tid;
        if (i < N_EDGES) p[i] = atomicAdd(&deg[row[i]], 1);
    } else {
        int i = ((int)blockIdx.x - CNT_BLOCKS) * 256 + tid;
        if (i < CONV_TOT) {
            int o = i % H;
            int t = i / H;
            int d = t % H;
            int lk = t / H;
            int ct = o >> 4, lc = o & 15;
            int ks = d >> 5, quad = (d >> 3) & 3, j = d & 7;
            wfrag[(size_t)lk * 9216 + ct * 1536 + ks * 512 + (quad * 16 + lc) * 8 + j] =
                (f16)conv_w[i];
        } else if (i < CONV_TOT + FC0_TOT) {
            int j = i - CONV_TOT;      // j = d*96+o
            int o = j % H, d = j / H;
            fc0t[o * DIN + d] = (f16)fc0_w[j];
        } else if (i < CONV_TOT + FC0_TOT + FC1_TOT) {
            int j = i - CONV_TOT - FC0_TOT;  // target [o][d]
            int o = j / H, d = j % H;
            fc1t[j] = (o < C_OUT) ? (f16)fc1_w[d * C_OUT + o] : (f16)0.f;
        }
    }
}

__global__ __launch_bounds__(1024) void scanA(const int* __restrict__ deg,
                                              int* __restrict__ rowptr,
                                              int* __restrict__ partial, int n) {
    __shared__ int wsum[16];
    int tid  = threadIdx.x;
    int lane = tid & 63, wid = tid >> 6;
    int idx = blockIdx.x * 1024 + tid;
    int v = (idx < n) ? deg[idx] : 0;
    int s = v;
    #pragma unroll
    for (int off = 1; off < 64; off <<= 1) {
        int t = __shfl_up(s, off, 64);
        if (lane >= off) s += t;
    }
    if (lane == 63) wsum[wid] = s;
    __syncthreads();
    if (wid == 0 && lane < 16) {
        int w = wsum[lane];
        #pragma unroll
        for (int off = 1; off < 16; off <<= 1) {
            int t = __shfl_up(w, off, 16);
            if (lane >= off) w += t;
        }
        wsum[lane] = w;
    }
    __syncthreads();
    int waveoff = (wid == 0) ? 0 : wsum[wid - 1];
    if (idx < n) rowptr[idx + 1] = waveoff + s;
    if (tid == 1023) partial[blockIdx.x] = waveoff + s;
}

__global__ __launch_bounds__(1024) void scanC(int* __restrict__ rowptr,
                                              const int* __restrict__ partial,
                                              int nb, int n) {
    __shared__ int boff_s;
    int tid = threadIdx.x;
    if (tid < 64) {
        int v = 0;
        for (int j = tid; j < (int)blockIdx.x; j += 64) v += partial[j];
        #pragma unroll
        for (int off = 32; off >= 1; off >>= 1) v += __shfl_xor(v, off, 64);
        if (tid == 0) boff_s = v;
    }
    __syncthreads();
    int boff = boff_s;
    int idx = blockIdx.x * 1024 + tid;
    if (idx == 0) rowptr[0] = 0;
    if (idx < n) rowptr[idx + 1] += boff;
}

__global__ __launch_bounds__(256) void scatter_store_xcd(const int* __restrict__ row,
                                                         const int* __restrict__ col,
                                                         const int* __restrict__ p,
                                                         const int* __restrict__ rowptr,
                                                         int* __restrict__ csr, int e) {
    int g = blockIdx.x & 7;
    int rlo = g * GSZ, rhi = rlo + GSZ;
    int stride = (gridDim.x >> 3) * 256;
    for (int i = (blockIdx.x >> 3) * 256 + threadIdx.x; i < e; i += stride) {
        int r = row[i];
        if (r >= rlo && r < rhi)
            csr[rowptr[r] + p[i]] = col[i];
    }
}

// ---------------- fused per-layer pre-pass: spmm + ctx softmax ----------------
// spmm: 16 rows/block, one row per 16-lane group -> 3125 blocks = full 32-wave
// occupancy and fine-grained load balance. Rows are unpadded (192B = 12 x 16B;
// lanes 12-15 idle on the gather, all lanes participate in index load+shuffle).
// Inner loop x4-unrolled (4 independent gathers in flight per lane) and the
// NEXT 16-index csr block is prefetched before the current block is consumed,
// taking the ~200cy L2 csr load off the critical path.

#define SPMM_BLOCKS ((N_NODES + 15) / 16)    // 3125
#define CTX_BLOCKS  ((N_NODES + 255) / 256)  // 196

__global__ __launch_bounds__(256) void layer_pre(const f16* __restrict__ h16,
                                                 const int* __restrict__ rowptr,
                                                 const int* __restrict__ csr,
                                                 f16* __restrict__ hi16,
                                                 const float* __restrict__ cw,
                                                 const float* __restrict__ cb,
                                                 float* __restrict__ zt, int n) {
    __shared__ float ws[H * K_EXP];
    __shared__ float bs[K_EXP];
    int tid = threadIdx.x;
    if ((int)blockIdx.x < SPMM_BLOCKS) {
        int r  = blockIdx.x * 16 + (tid >> 4);
        int li = tid & 15;
        if (r >= n) return;
        bool act = li < 12;
        int j = rowptr[r], e = rowptr[r + 1];
        float acc[8] = {};
        const f16* hb = h16 + li * 8;
        int m = e - j; if (m > 16) m = 16;
        int c = 0;
        if (li < m) c = csr[j + li];
        while (j < e) {
            // prefetch next 16-index block
            int jn = j + m;
            int mn = e - jn; if (mn > 16) mn = 16;
            int cn = 0;
            if (mn > 0 && li < mn) cn = csr[jn + li];
            int t = 0;
            // x4 unrolled: 4 independent gathers in flight
            for (; t + 4 <= m; t += 4) {
                int c0 = __shfl(c, t, 16),     c1 = __shfl(c, t + 1, 16);
                int c2 = __shfl(c, t + 2, 16), c3 = __shfl(c, t + 3, 16);
                f16x8 v0 = {}, v1 = {}, v2 = {}, v3 = {};
                if (act) {
                    v0 = *(const f16x8*)(hb + (size_t)c0 * H);
                    v1 = *(const f16x8*)(hb + (size_t)c1 * H);
                    v2 = *(const f16x8*)(hb + (size_t)c2 * H);
                    v3 = *(const f16x8*)(hb + (size_t)c3 * H);
                }
                #pragma unroll
                for (int q = 0; q < 8; q++) acc[q] += (float)v0[q];
                #pragma unroll
                for (int q = 0; q < 8; q++) acc[q] += (float)v1[q];
                #pragma unroll
                for (int q = 0; q < 8; q++) acc[q] += (float)v2[q];
                #pragma unroll
                for (int q = 0; q < 8; q++) acc[q] += (float)v3[q];
            }
            for (; t < m; t++) {
                int cc = __shfl(c, t, 16);
                f16x8 v = {};
                if (act) v = *(const f16x8*)(hb + (size_t)cc * H);
                #pragma unroll
                for (int q = 0; q < 8; q++) acc[q] += (float)v[q];
            }
            j = jn; m = mn; c = cn;
        }
        if (act) {
            f16x8 o;
            #pragma unroll
            for (int q = 0; q < 8; q++) o[q] = (f16)acc[q];
            *(f16x8*)(hi16 + (size_t)r * H + li * 8) = o;
        }
    } else {
        for (int t = tid; t < H * K_EXP; t += 256) ws[t] = cw[t];
        if (tid < K_EXP) bs[tid] = cb[tid];
        __syncthreads();
        int node = ((int)blockIdx.x - SPMM_BLOCKS) * 256 + tid;
        if (node >= n) return;
        float acc[K_EXP];
        #pragma unroll
        for (int k = 0; k < K_EXP; k++) acc[k] = bs[k];
        const f16* hr = h16 + (size_t)node * H;
        #pragma unroll 3
        for (int c8 = 0; c8 < 12; c8++) {
            f16x8 v = *(const f16x8*)(hr + c8 * 8);
            #pragma unroll
            for (int j = 0; j < 8; j++) {
                float hv = (float)v[j];
                int d = c8 * 8 + j;
                #pragma unroll
                for (int k = 0; k < K_EXP; k++) acc[k] += hv * ws[d * K_EXP + k];
            }
        }
        float mx = acc[0];
        #pragma unroll
        for (int k = 1; k < K_EXP; k++) mx = fmaxf(mx, acc[k]);
        float s = 0.f;
        #pragma unroll
        for (int k = 0; k < K_EXP; k++) { acc[k] = __expf(acc[k] - mx); s += acc[k]; }
        float inv = 1.f / s;
        #pragma unroll
        for (int k = 0; k < K_EXP; k++)
            zt[(size_t)k * N_NODES + node] = acc[k] * inv;
    }
}

// ---------------- fc0 via fp16 MFMA (writes fp16 h only) ----------------

#define FPAD 136

__global__ __launch_bounds__(256) void fc0_kernel(const float* __restrict__ x,
                                                  const f16* __restrict__ fc0t,
                                                  const float* __restrict__ b,
                                                  f16* __restrict__ h16, int n) {
    __shared__ f16 As[64 * FPAD];
    __shared__ f16 Ws[96 * FPAD];
    int tid = threadIdx.x;
    int l = tid & 63, w = tid >> 6;
    int quad = l >> 4, lc = l & 15;
    int row0 = blockIdx.x * 64;

    for (int t = tid; t < 2048; t += 256) {
        int m = t >> 5, c4 = (t & 31) * 4;
        int gr = row0 + m;
        float4 v = {0.f, 0.f, 0.f, 0.f};
        if (gr < n) v = *(const float4*)(x + (size_t)gr * DIN + c4);
        f16x4 h4 = {(f16)v.x, (f16)v.y, (f16)v.z, (f16)v.w};
        *(f16x4*)&As[m * FPAD + c4] = h4;
    }
    for (int t = tid; t < 1536; t += 256) {
        int o = t >> 4, c8 = (t & 15) * 8;
        *(f16x8*)&Ws[o * FPAD + c8] = *(const f16x8*)(fc0t + o * DIN + c8);
    }
    __syncthreads();

    f16x8 afr[4];
    #pragma unroll
    for (int ks = 0; ks < 4; ks++)
        afr[ks] = *(const f16x8*)&As[(16 * w + lc) * FPAD + ks * 32 + quad * 8];

    f32x4 acc[6] = {};
    #pragma unroll
    for (int ct = 0; ct < 6; ct++) {
        #pragma unroll
        for (int ks = 0; ks < 4; ks++) {
            f16x8 bfr = *(const f16x8*)&Ws[(ct * 16 + lc) * FPAD + ks * 32 + quad * 8];
            acc[ct] = __builtin_amdgcn_mfma_f32_16x16x32_f16(afr[ks], bfr, acc[ct], 0, 0, 0);
        }
    }

    int m0 = 16 * w + quad * 4;
    #pragma unroll
    for (int r = 0; r < 4; r++) {
        int gr = row0 + m0 + r;
        if (gr < n) {
            #pragma unroll
            for (int ct = 0; ct < 6; ct++) {
                int o = ct * 16 + lc;
                h16[(size_t)gr * H + o] = (f16)fmaxf(acc[ct][r] + b[o], 0.f);
            }
        }
    }
}

// ---------------- expert GEMM: 128 rows/block, LDS-staged fragment weights ----------------

#define EG_STAGE 2
#define EG_HALFS (EG_STAGE * 9216)   // 18432 halfs = 36 KB

__global__ __launch_bounds__(256) void expert_gemm(const f16* __restrict__ hi16,
                                                   const f16* __restrict__ hin16,
                                                   const f16* __restrict__ wfrag, // [K][9216]
                                                   const float* __restrict__ zt,  // [K][N]
                                                   f16* __restrict__ hout16, int n) {
    __shared__ f16 Wl[EG_HALFS];
    int tid = threadIdx.x;
    int l = tid & 63, w = tid >> 6;
    int quad = l >> 4, lc = l & 15;
    int brow = blockIdx.x * 128;
    int wrow0 = brow + w * 16;          // M-tile 0 for this wave
    int wrow1 = wrow0 + 64;             // M-tile 1

    f16x8 afr0[3], afr1[3];
    #pragma unroll
    for (int ks = 0; ks < 3; ks++) {
        afr0[ks] = *(const f16x8*)(hi16 + (size_t)(wrow0 + lc) * H + ks * 32 + quad * 8);
        afr1[ks] = *(const f16x8*)(hi16 + (size_t)(wrow1 + lc) * H + ks * 32 + quad * 8);
    }

    f32x4 acc0[6] = {};
    f32x4 acc1[6] = {};

    for (int kb = 0; kb < K_EXP; kb += EG_STAGE) {
        __syncthreads();
        const f16* src = wfrag + (size_t)kb * 9216;
        for (int t = tid; t < EG_HALFS / 8; t += 256)
            *(f16x8*)&Wl[t * 8] = *(const f16x8*)(src + t * 8);
        __syncthreads();

        #pragma unroll
        for (int k2 = 0; k2 < EG_STAGE; k2++) {
            int k = kb + k2;
            f32x4 zf0 = *(const f32x4*)(zt + (size_t)k * N_NODES + wrow0 + quad * 4);
            f32x4 zf1 = *(const f32x4*)(zt + (size_t)k * N_NODES + wrow1 + quad * 4);
            #pragma unroll
            for (int ct = 0; ct < 6; ct++) {
                f16x8 b0 = *(const f16x8*)&Wl[k2 * 9216 + ct * 1536 + 0 * 512 + l * 8];
                f16x8 b1 = *(const f16x8*)&Wl[k2 * 9216 + ct * 1536 + 1 * 512 + l * 8];
                f16x8 b2 = *(const f16x8*)&Wl[k2 * 9216 + ct * 1536 + 2 * 512 + l * 8];
                f32x4 t0 = {};
                t0 = __builtin_amdgcn_mfma_f32_16x16x32_f16(afr0[0], b0, t0, 0, 0, 0);
                t0 = __builtin_amdgcn_mfma_f32_16x16x32_f16(afr0[1], b1, t0, 0, 0, 0);
                t0 = __builtin_amdgcn_mfma_f32_16x16x32_f16(afr0[2], b2, t0, 0, 0, 0);
                acc0[ct] += zf0 * t0;
                f32x4 t1 = {};
                t1 = __builtin_amdgcn_mfma_f32_16x16x32_f16(afr1[0], b0, t1, 0, 0, 0);
                t1 = __builtin_amdgcn_mfma_f32_16x16x32_f16(afr1[1], b1, t1, 0, 0, 0);
                t1 = __builtin_amdgcn_mfma_f32_16x16x32_f16(afr1[2], b2, t1, 0, 0, 0);
                acc1[ct] += zf1 * t1;
            }
        }
    }

    #pragma unroll
    for (int r = 0; r < 4; r++) {
        int gr0 = wrow0 + quad * 4 + r;
        if (gr0 < n) {
            #pragma unroll
            for (int ct = 0; ct < 6; ct++) {
                int o = ct * 16 + lc;
                float v = fmaxf(acc0[ct][r] + (float)hin16[(size_t)gr0 * H + o], 0.f);
                hout16[(size_t)gr0 * H + o] = (f16)v;
            }
        }
        int gr1 = wrow1 + quad * 4 + r;
        if (gr1 < n) {
            #pragma unroll
            for (int ct = 0; ct < 6; ct++) {
                int o = ct * 16 + lc;
                float v = fmaxf(acc1[ct][r] + (float)hin16[(size_t)gr1 * H + o], 0.f);
                hout16[(size_t)gr1 * H + o] = (f16)v;
            }
        }
    }
}

// ---------------- fc1 via fp16 MFMA ----------------

#define APAD 104

__global__ __launch_bounds__(256) void fc1_kernel(const f16* __restrict__ h16,
                                                  const f16* __restrict__ fc1t,
                                                  const float* __restrict__ b,
                                                  float* __restrict__ out, int n) {
    __shared__ f16 As[64 * APAD];
    __shared__ f16 Ws[48 * APAD];
    int tid = threadIdx.x;
    int l = tid & 63, w = tid >> 6;
    int quad = l >> 4, lc = l & 15;
    int row0 = blockIdx.x * 64;

    for (int t = tid; t < 768; t += 256) {
        int m = t / 12, c8 = (t % 12) * 8;
        int gr = row0 + m;
        f16x8 v = {};
        if (gr < n) v = *(const f16x8*)(h16 + (size_t)gr * H + c8);
        *(f16x8*)&As[m * APAD + c8] = v;
    }
    for (int t = tid; t < 576; t += 256) {
        int o = t / 12, c8 = (t % 12) * 8;
        *(f16x8*)&Ws[o * APAD + c8] = *(const f16x8*)(fc1t + o * H + c8);
    }
    __syncthreads();

    f16x8 afr[3];
    #pragma unroll
    for (int ks = 0; ks < 3; ks++)
        afr[ks] = *(const f16x8*)&As[(16 * w + lc) * APAD + ks * 32 + quad * 8];

    f32x4 acc[3] = {};
    #pragma unroll
    for (int ct = 0; ct < 3; ct++) {
        #pragma unroll
        for (int ks = 0; ks < 3; ks++) {
            f16x8 bfr = *(const f16x8*)&Ws[(ct * 16 + lc) * APAD + ks * 32 + quad * 8];
            acc[ct] = __builtin_amdgcn_mfma_f32_16x16x32_f16(afr[ks], bfr, acc[ct], 0, 0, 0);
        }
    }

    int m0 = 16 * w + quad * 4;
    #pragma unroll
    for (int r = 0; r < 4; r++) {
        int gr = row0 + m0 + r;
        if (gr < n) {
            #pragma unroll
            for (int ct = 0; ct < 3; ct++) {
                int o = ct * 16 + lc;
                if (o < C_OUT)
                    out[(size_t)gr * C_OUT + o] = acc[ct][r] + b[o];
            }
        }
    }
}

// ---------------- launch ----------------

extern "C" void kernel_launch(void* const* d_in, const int* in_sizes, int n_in,
                              void* d_out, int out_size, void* d_ws, size_t ws_size,
                              hipStream_t stream) {
    const float* x      = (const float*)d_in[0];
    const int*   ei     = (const int*)d_in[1];
    const float* fc0_w  = (const float*)d_in[2];
    const float* fc0_b  = (const float*)d_in[3];
    const float* fc1_w  = (const float*)d_in[4];
    const float* fc1_b  = (const float*)d_in[5];
    const float* ctx_w  = (const float*)d_in[6];
    const float* ctx_b  = (const float*)d_in[7];
    const float* conv_w = (const float*)d_in[8];
    float* out = (float*)d_out;

    const size_t NH = (size_t)N_NODES * H;

    float* zbuf = (float*)d_ws;                          // [K][N] transposed
    f16*   h16a = (f16*)(zbuf + (size_t)N_NODES * K_EXP);
    f16*   h16b = h16a + NH;
    f16*   hi16 = h16b + NH;
    f16*   wfrag= hi16 + NH;
    f16*   fc0t = wfrag + CONV_TOT;
    f16*   fc1t = fc0t + FC0_TOT;
    int* rowptr = (int*)(fc1t + FC1_TOT);                // N+1
    int* deg    = rowptr + (N_NODES + 1);                // N
    int* csr    = deg + N_NODES;                         // E
    int* prank  = csr + N_EDGES;                         // E
    int* partial  = prank + N_EDGES;                     // 64

    const int* row = ei;
    const int* col = ei + N_EDGES;

    hipMemsetAsync(deg, 0, sizeof(int) * N_NODES, stream);

    count_convert<<<CNT_BLOCKS + CVT_BLOCKS, 256, 0, stream>>>(
        row, deg, prank, conv_w, fc0_w, fc1_w, wfrag, fc0t, fc1t);
    int nsb = (N_NODES + 1023) / 1024;   // 49
    scanA<<<nsb, 1024, 0, stream>>>(deg, rowptr, partial, N_NODES);
    scanC<<<nsb, 1024, 0, stream>>>(rowptr, partial, nsb, N_NODES);
    scatter_store_xcd<<<1024, 256, 0, stream>>>(row, col, prank, rowptr, csr, N_EDGES);

    int gemm_grid = (N_NODES + 63) / 64;   // 782
    fc0_kernel<<<gemm_grid, 256, 0, stream>>>(x, fc0t, fc0_b, h16a, N_NODES);

    int eg_grid = (N_NODES + 127) / 128;   // 391
    f16* hcur = h16a;
    f16* hnext = h16b;
    for (int i = 0; i < L_LAYERS; i++) {
        layer_pre<<<SPMM_BLOCKS + CTX_BLOCKS, 256, 0, stream>>>(
            hcur, rowptr, csr, hi16,
            ctx_w + (size_t)i * H * K_EXP, ctx_b + (size_t)i * K_EXP, zbuf, N_NODES);
        expert_gemm<<<eg_grid, 256, 0, stream>>>(
            hi16, hcur, wfrag + (size_t)i * K_EXP * H * H, zbuf, hnext, N_NODES);
        f16* t = hcur; hcur = hnext; hnext = t;
    }
    fc1_kernel<<<gemm_grid, 256, 0, stream>>>(hcur, fc1t, fc1_b, out, N_NODES);
}

// Round 5
// 369.747 us; speedup vs baseline: 1.1530x; 1.0386x over previous
//
#include <hip/hip_runtime.h>

#define N_NODES 50000
#define N_EDGES 800000
#define DIN     128
#define H       96
#define K_EXP   8
#define L_LAYERS 4
#define C_OUT   40

#define GSZ 6250   // rows per XCD group = N_NODES/8

typedef _Float16 f16;
typedef f16 f16x2 __attribute__((ext_vector_type(2)));
typedef f16 f16x4 __attribute__((ext_vector_type(4)));
typedef f16 f16x8 __attribute__((ext_vector_type(8)));
typedef float f32x4 __attribute__((ext_vector_type(4)));

// ---------------- CSR build + weight conversion (merged) ----------------

#define CONV_TOT (L_LAYERS * K_EXP * H * H)   // 294912
#define FC0_TOT  (DIN * H)                    // 12288
#define FC1_TOT  (48 * H)                     // 4608
#define CNT_BLOCKS ((N_EDGES + 255) / 256)            // 3125
#define CVT_BLOCKS ((CONV_TOT + FC0_TOT + FC1_TOT + 255) / 256)  // 1218

__global__ __launch_bounds__(256) void count_convert(const int* __restrict__ row,
                                                     int* __restrict__ deg,
                                                     int* __restrict__ p,
                                                     const float* __restrict__ conv_w,
                                                     const float* __restrict__ fc0_w,
                                                     const float* __restrict__ fc1_w,
                                                     f16* __restrict__ wfrag,
                                                     f16* __restrict__ fc0t,
                                                     f16* __restrict__ fc1t) {
    int tid = threadIdx.x;
    if ((int)blockIdx.x < CNT_BLOCKS) {
        int i = blockIdx.x * 256 + tid;
        if (i < N_EDGES) p[i] = atomicAdd(&deg[row[i]], 1);
    } else {
        int i = ((int)blockIdx.x - CNT_BLOCKS) * 256 + tid;
        if (i < CONV_TOT) {
            int o = i % H;
            int t = i / H;
            int d = t % H;
            int lk = t / H;
            int ct = o >> 4, lc = o & 15;
            int ks = d >> 5, quad = (d >> 3) & 3, j = d & 7;
            wfrag[(size_t)lk * 9216 + ct * 1536 + ks * 512 + (quad * 16 + lc) * 8 + j] =
                (f16)conv_w[i];
        } else if (i < CONV_TOT + FC0_TOT) {
            int j = i - CONV_TOT;      // j = d*96+o
            int o = j % H, d = j / H;
            fc0t[o * DIN + d] = (f16)fc0_w[j];
        } else if (i < CONV_TOT + FC0_TOT + FC1_TOT) {
            int j = i - CONV_TOT - FC0_TOT;  // target [o][d]
            int o = j / H, d = j % H;
            fc1t[j] = (o < C_OUT) ? (f16)fc1_w[d * C_OUT + o] : (f16)0.f;
        }
    }
}

__global__ __launch_bounds__(1024) void scanA(const int* __restrict__ deg,
                                              int* __restrict__ rowptr,
                                              int* __restrict__ partial, int n) {
    __shared__ int wsum[16];
    int tid  = threadIdx.x;
    int lane = tid & 63, wid = tid >> 6;
    int idx = blockIdx.x * 1024 + tid;
    int v = (idx < n) ? deg[idx] : 0;
    int s = v;
    #pragma unroll
    for (int off = 1; off < 64; off <<= 1) {
        int t = __shfl_up(s, off, 64);
        if (lane >= off) s += t;
    }
    if (lane == 63) wsum[wid] = s;
    __syncthreads();
    if (wid == 0 && lane < 16) {
        int w = wsum[lane];
        #pragma unroll
        for (int off = 1; off < 16; off <<= 1) {
            int t = __shfl_up(w, off, 16);
            if (lane >= off) w += t;
        }
        wsum[lane] = w;
    }
    __syncthreads();
    int waveoff = (wid == 0) ? 0 : wsum[wid - 1];
    if (idx < n) rowptr[idx + 1] = waveoff + s;
    if (tid == 1023) partial[blockIdx.x] = waveoff + s;
}

__global__ __launch_bounds__(1024) void scanC(int* __restrict__ rowptr,
                                              const int* __restrict__ partial,
                                              int nb, int n) {
    __shared__ int boff_s;
    int tid = threadIdx.x;
    if (tid < 64) {
        int v = 0;
        for (int j = tid; j < (int)blockIdx.x; j += 64) v += partial[j];
        #pragma unroll
        for (int off = 32; off >= 1; off >>= 1) v += __shfl_xor(v, off, 64);
        if (tid == 0) boff_s = v;
    }
    __syncthreads();
    int boff = boff_s;
    int idx = blockIdx.x * 1024 + tid;
    if (idx == 0) rowptr[0] = 0;
    if (idx < n) rowptr[idx + 1] += boff;
}

__global__ __launch_bounds__(256) void scatter_store_xcd(const int* __restrict__ row,
                                                         const int* __restrict__ col,
                                                         const int* __restrict__ p,
                                                         const int* __restrict__ rowptr,
                                                         int* __restrict__ csr, int e) {
    int g = blockIdx.x & 7;
    int rlo = g * GSZ, rhi = rlo + GSZ;
    int stride = (gridDim.x >> 3) * 256;
    for (int i = (blockIdx.x >> 3) * 256 + threadIdx.x; i < e; i += stride) {
        int r = row[i];
        if (r >= rlo && r < rhi)
            csr[rowptr[r] + p[i]] = col[i];
    }
}

// ---------------- fused per-layer pre-pass: spmm + ctx softmax ----------------
// spmm: 16 rows/block, one row per 16-lane group (3125 blocks, full occupancy).
// NO cross-lane ops on the critical path: the group's column indices are
// wave-group-uniform, so every lane loads the index quad directly from csr
// (same 16B -> one coalesced L1-hot request). 8 independent gathers in flight
// per lane per iteration + next-quad index prefetch.
// Over-read safety: up to 16 ints past a row's csr range are read; they land
// in later rows' indices or in prank[] (values < 64) -- all valid node ids --
// and their contribution is masked out of the accumulator.

#define SPMM_BLOCKS ((N_NODES + 15) / 16)    // 3125
#define CTX_BLOCKS  ((N_NODES + 255) / 256)  // 196

#define ACC8(v) { _Pragma("unroll") for (int q = 0; q < 8; q++) acc[q] += (float)(v)[q]; }

__global__ __launch_bounds__(256) void layer_pre(const f16* __restrict__ h16,
                                                 const int* __restrict__ rowptr,
                                                 const int* __restrict__ csr,
                                                 f16* __restrict__ hi16,
                                                 const float* __restrict__ cw,
                                                 const float* __restrict__ cb,
                                                 float* __restrict__ zt, int n) {
    __shared__ float ws[H * K_EXP];
    __shared__ float bs[K_EXP];
    int tid = threadIdx.x;
    if ((int)blockIdx.x < SPMM_BLOCKS) {
        int r  = blockIdx.x * 16 + (tid >> 4);
        int li = tid & 15;
        if (r >= n) return;
        bool act = li < 12;
        int j = rowptr[r], e = rowptr[r + 1];
        float acc[8] = {};
        const f16* hb = h16 + li * 8;

        int4 qa = *(const int4*)(csr + j);       // overread-safe
        int4 qb = *(const int4*)(csr + j + 4);

        while (j + 8 <= e) {
            int4 na = *(const int4*)(csr + j + 8);    // prefetch next iter
            int4 nb = *(const int4*)(csr + j + 12);
            f16x8 v0 = {}, v1 = {}, v2 = {}, v3 = {}, v4 = {}, v5 = {}, v6 = {}, v7 = {};
            if (act) {
                v0 = *(const f16x8*)(hb + (size_t)qa.x * H);
                v1 = *(const f16x8*)(hb + (size_t)qa.y * H);
                v2 = *(const f16x8*)(hb + (size_t)qa.z * H);
                v3 = *(const f16x8*)(hb + (size_t)qa.w * H);
                v4 = *(const f16x8*)(hb + (size_t)qb.x * H);
                v5 = *(const f16x8*)(hb + (size_t)qb.y * H);
                v6 = *(const f16x8*)(hb + (size_t)qb.z * H);
                v7 = *(const f16x8*)(hb + (size_t)qb.w * H);
            }
            ACC8(v0) ACC8(v1) ACC8(v2) ACC8(v3)
            ACC8(v4) ACC8(v5) ACC8(v6) ACC8(v7)
            j += 8; qa = na; qb = nb;
        }
        if (j + 4 <= e) {
            f16x8 v0 = {}, v1 = {}, v2 = {}, v3 = {};
            if (act) {
                v0 = *(const f16x8*)(hb + (size_t)qa.x * H);
                v1 = *(const f16x8*)(hb + (size_t)qa.y * H);
                v2 = *(const f16x8*)(hb + (size_t)qa.z * H);
                v3 = *(const f16x8*)(hb + (size_t)qa.w * H);
            }
            ACC8(v0) ACC8(v1) ACC8(v2) ACC8(v3)
            j += 4; qa = qb;
        }
        int rem = e - j;   // 0..3
        if (rem > 0) {
            f16x8 v0 = {}, v1 = {}, v2 = {};
            if (act) {
                v0 = *(const f16x8*)(hb + (size_t)qa.x * H);
                if (rem > 1) v1 = *(const f16x8*)(hb + (size_t)qa.y * H);
                if (rem > 2) v2 = *(const f16x8*)(hb + (size_t)qa.z * H);
            }
            ACC8(v0)
            if (rem > 1) ACC8(v1)
            if (rem > 2) ACC8(v2)
        }
        if (act) {
            f16x8 o;
            #pragma unroll
            for (int q = 0; q < 8; q++) o[q] = (f16)acc[q];
            *(f16x8*)(hi16 + (size_t)r * H + li * 8) = o;
        }
    } else {
        for (int t = tid; t < H * K_EXP; t += 256) ws[t] = cw[t];
        if (tid < K_EXP) bs[tid] = cb[tid];
        __syncthreads();
        int node = ((int)blockIdx.x - SPMM_BLOCKS) * 256 + tid;
        if (node >= n) return;
        float acc[K_EXP];
        #pragma unroll
        for (int k = 0; k < K_EXP; k++) acc[k] = bs[k];
        const f16* hr = h16 + (size_t)node * H;
        #pragma unroll 3
        for (int c8 = 0; c8 < 12; c8++) {
            f16x8 v = *(const f16x8*)(hr + c8 * 8);
            #pragma unroll
            for (int j = 0; j < 8; j++) {
                float hv = (float)v[j];
                int d = c8 * 8 + j;
                #pragma unroll
                for (int k = 0; k < K_EXP; k++) acc[k] += hv * ws[d * K_EXP + k];
            }
        }
        float mx = acc[0];
        #pragma unroll
        for (int k = 1; k < K_EXP; k++) mx = fmaxf(mx, acc[k]);
        float s = 0.f;
        #pragma unroll
        for (int k = 0; k < K_EXP; k++) { acc[k] = __expf(acc[k] - mx); s += acc[k]; }
        float inv = 1.f / s;
        #pragma unroll
        for (int k = 0; k < K_EXP; k++)
            zt[(size_t)k * N_NODES + node] = acc[k] * inv;
    }
}

// ---------------- fc0 via fp16 MFMA (writes fp16 h only) ----------------

#define FPAD 136

__global__ __launch_bounds__(256) void fc0_kernel(const float* __restrict__ x,
                                                  const f16* __restrict__ fc0t,
                                                  const float* __restrict__ b,
                                                  f16* __restrict__ h16, int n) {
    __shared__ f16 As[64 * FPAD];
    __shared__ f16 Ws[96 * FPAD];
    int tid = threadIdx.x;
    int l = tid & 63, w = tid >> 6;
    int quad = l >> 4, lc = l & 15;
    int row0 = blockIdx.x * 64;

    for (int t = tid; t < 2048; t += 256) {
        int m = t >> 5, c4 = (t & 31) * 4;
        int gr = row0 + m;
        float4 v = {0.f, 0.f, 0.f, 0.f};
        if (gr < n) v = *(const float4*)(x + (size_t)gr * DIN + c4);
        f16x4 h4 = {(f16)v.x, (f16)v.y, (f16)v.z, (f16)v.w};
        *(f16x4*)&As[m * FPAD + c4] = h4;
    }
    for (int t = tid; t < 1536; t += 256) {
        int o = t >> 4, c8 = (t & 15) * 8;
        *(f16x8*)&Ws[o * FPAD + c8] = *(const f16x8*)(fc0t + o * DIN + c8);
    }
    __syncthreads();

    f16x8 afr[4];
    #pragma unroll
    for (int ks = 0; ks < 4; ks++)
        afr[ks] = *(const f16x8*)&As[(16 * w + lc) * FPAD + ks * 32 + quad * 8];

    f32x4 acc[6] = {};
    #pragma unroll
    for (int ct = 0; ct < 6; ct++) {
        #pragma unroll
        for (int ks = 0; ks < 4; ks++) {
            f16x8 bfr = *(const f16x8*)&Ws[(ct * 16 + lc) * FPAD + ks * 32 + quad * 8];
            acc[ct] = __builtin_amdgcn_mfma_f32_16x16x32_f16(afr[ks], bfr, acc[ct], 0, 0, 0);
        }
    }

    int m0 = 16 * w + quad * 4;
    #pragma unroll
    for (int r = 0; r < 4; r++) {
        int gr = row0 + m0 + r;
        if (gr < n) {
            #pragma unroll
            for (int ct = 0; ct < 6; ct++) {
                int o = ct * 16 + lc;
                h16[(size_t)gr * H + o] = (f16)fmaxf(acc[ct][r] + b[o], 0.f);
            }
        }
    }
}

// ---------------- expert GEMM: 128 rows/block, LDS-staged fragment weights ----------------

#define EG_STAGE 2
#define EG_HALFS (EG_STAGE * 9216)   // 18432 halfs = 36 KB

__global__ __launch_bounds__(256) void expert_gemm(const f16* __restrict__ hi16,
                                                   const f16* __restrict__ hin16,
                                                   const f16* __restrict__ wfrag, // [K][9216]
                                                   const float* __restrict__ zt,  // [K][N]
                                                   f16* __restrict__ hout16, int n) {
    __shared__ f16 Wl[EG_HALFS];
    int tid = threadIdx.x;
    int l = tid & 63, w = tid >> 6;
    int quad = l >> 4, lc = l & 15;
    int brow = blockIdx.x * 128;
    int wrow0 = brow + w * 16;          // M-tile 0 for this wave
    int wrow1 = wrow0 + 64;             // M-tile 1

    f16x8 afr0[3], afr1[3];
    #pragma unroll
    for (int ks = 0; ks < 3; ks++) {
        afr0[ks] = *(const f16x8*)(hi16 + (size_t)(wrow0 + lc) * H + ks * 32 + quad * 8);
        afr1[ks] = *(const f16x8*)(hi16 + (size_t)(wrow1 + lc) * H + ks * 32 + quad * 8);
    }

    f32x4 acc0[6] = {};
    f32x4 acc1[6] = {};

    for (int kb = 0; kb < K_EXP; kb += EG_STAGE) {
        __syncthreads();
        const f16* src = wfrag + (size_t)kb * 9216;
        for (int t = tid; t < EG_HALFS / 8; t += 256)
            *(f16x8*)&Wl[t * 8] = *(const f16x8*)(src + t * 8);
        __syncthreads();

        #pragma unroll
        for (int k2 = 0; k2 < EG_STAGE; k2++) {
            int k = kb + k2;
            f32x4 zf0 = *(const f32x4*)(zt + (size_t)k * N_NODES + wrow0 + quad * 4);
            f32x4 zf1 = *(const f32x4*)(zt + (size_t)k * N_NODES + wrow1 + quad * 4);
            #pragma unroll
            for (int ct = 0; ct < 6; ct++) {
                f16x8 b0 = *(const f16x8*)&Wl[k2 * 9216 + ct * 1536 + 0 * 512 + l * 8];
                f16x8 b1 = *(const f16x8*)&Wl[k2 * 9216 + ct * 1536 + 1 * 512 + l * 8];
                f16x8 b2 = *(const f16x8*)&Wl[k2 * 9216 + ct * 1536 + 2 * 512 + l * 8];
                f32x4 t0 = {};
                t0 = __builtin_amdgcn_mfma_f32_16x16x32_f16(afr0[0], b0, t0, 0, 0, 0);
                t0 = __builtin_amdgcn_mfma_f32_16x16x32_f16(afr0[1], b1, t0, 0, 0, 0);
                t0 = __builtin_amdgcn_mfma_f32_16x16x32_f16(afr0[2], b2, t0, 0, 0, 0);
                acc0[ct] += zf0 * t0;
                f32x4 t1 = {};
                t1 = __builtin_amdgcn_mfma_f32_16x16x32_f16(afr1[0], b0, t1, 0, 0, 0);
                t1 = __builtin_amdgcn_mfma_f32_16x16x32_f16(afr1[1], b1, t1, 0, 0, 0);
                t1 = __builtin_amdgcn_mfma_f32_16x16x32_f16(afr1[2], b2, t1, 0, 0, 0);
                acc1[ct] += zf1 * t1;
            }
        }
    }

    #pragma unroll
    for (int r = 0; r < 4; r++) {
        int gr0 = wrow0 + quad * 4 + r;
        if (gr0 < n) {
            #pragma unroll
            for (int ct = 0; ct < 6; ct++) {
                int o = ct * 16 + lc;
                float v = fmaxf(acc0[ct][r] + (float)hin16[(size_t)gr0 * H + o], 0.f);
                hout16[(size_t)gr0 * H + o] = (f16)v;
            }
        }
        int gr1 = wrow1 + quad * 4 + r;
        if (gr1 < n) {
            #pragma unroll
            for (int ct = 0; ct < 6; ct++) {
                int o = ct * 16 + lc;
                float v = fmaxf(acc1[ct][r] + (float)hin16[(size_t)gr1 * H + o], 0.f);
                hout16[(size_t)gr1 * H + o] = (f16)v;
            }
        }
    }
}

// ---------------- fc1 via fp16 MFMA ----------------

#define APAD 104

__global__ __launch_bounds__(256) void fc1_kernel(const f16* __restrict__ h16,
                                                  const f16* __restrict__ fc1t,
                                                  const float* __restrict__ b,
                                                  float* __restrict__ out, int n) {
    __shared__ f16 As[64 * APAD];
    __shared__ f16 Ws[48 * APAD];
    int tid = threadIdx.x;
    int l = tid & 63, w = tid >> 6;
    int quad = l >> 4, lc = l & 15;
    int row0 = blockIdx.x * 64;

    for (int t = tid; t < 768; t += 256) {
        int m = t / 12, c8 = (t % 12) * 8;
        int gr = row0 + m;
        f16x8 v = {};
        if (gr < n) v = *(const f16x8*)(h16 + (size_t)gr * H + c8);
        *(f16x8*)&As[m * APAD + c8] = v;
    }
    for (int t = tid; t < 576; t += 256) {
        int o = t / 12, c8 = (t % 12) * 8;
        *(f16x8*)&Ws[o * APAD + c8] = *(const f16x8*)(fc1t + o * H + c8);
    }
    __syncthreads();

    f16x8 afr[3];
    #pragma unroll
    for (int ks = 0; ks < 3; ks++)
        afr[ks] = *(const f16x8*)&As[(16 * w + lc) * APAD + ks * 32 + quad * 8];

    f32x4 acc[3] = {};
    #pragma unroll
    for (int ct = 0; ct < 3; ct++) {
        #pragma unroll
        for (int ks = 0; ks < 3; ks++) {
            f16x8 bfr = *(const f16x8*)&Ws[(ct * 16 + lc) * APAD + ks * 32 + quad * 8];
            acc[ct] = __builtin_amdgcn_mfma_f32_16x16x32_f16(afr[ks], bfr, acc[ct], 0, 0, 0);
        }
    }

    int m0 = 16 * w + quad * 4;
    #pragma unroll
    for (int r = 0; r < 4; r++) {
        int gr = row0 + m0 + r;
        if (gr < n) {
            #pragma unroll
            for (int ct = 0; ct < 3; ct++) {
                int o = ct * 16 + lc;
                if (o < C_OUT)
                    out[(size_t)gr * C_OUT + o] = acc[ct][r] + b[o];
            }
        }
    }
}

// ---------------- launch ----------------

extern "C" void kernel_launch(void* const* d_in, const int* in_sizes, int n_in,
                              void* d_out, int out_size, void* d_ws, size_t ws_size,
                              hipStream_t stream) {
    const float* x      = (const float*)d_in[0];
    const int*   ei     = (const int*)d_in[1];
    const float* fc0_w  = (const float*)d_in[2];
    const float* fc0_b  = (const float*)d_in[3];
    const float* fc1_w  = (const float*)d_in[4];
    const float* fc1_b  = (const float*)d_in[5];
    const float* ctx_w  = (const float*)d_in[6];
    const float* ctx_b  = (const float*)d_in[7];
    const float* conv_w = (const float*)d_in[8];
    float* out = (float*)d_out;

    const size_t NH = (size_t)N_NODES * H;

    float* zbuf = (float*)d_ws;                          // [K][N] transposed
    f16*   h16a = (f16*)(zbuf + (size_t)N_NODES * K_EXP);
    f16*   h16b = h16a + NH;
    f16*   hi16 = h16b + NH;
    f16*   wfrag= hi16 + NH;
    f16*   fc0t = wfrag + CONV_TOT;
    f16*   fc1t = fc0t + FC0_TOT;
    int* rowptr = (int*)(fc1t + FC1_TOT);                // N+1
    int* deg    = rowptr + (N_NODES + 1);                // N
    int* csr    = deg + N_NODES;                         // E
    int* prank  = csr + N_EDGES;                         // E  (also csr overread pad)
    int* partial  = prank + N_EDGES;                     // 64

    const int* row = ei;
    const int* col = ei + N_EDGES;

    hipMemsetAsync(deg, 0, sizeof(int) * N_NODES, stream);

    count_convert<<<CNT_BLOCKS + CVT_BLOCKS, 256, 0, stream>>>(
        row, deg, prank, conv_w, fc0_w, fc1_w, wfrag, fc0t, fc1t);
    int nsb = (N_NODES + 1023) / 1024;   // 49
    scanA<<<nsb, 1024, 0, stream>>>(deg, rowptr, partial, N_NODES);
    scanC<<<nsb, 1024, 0, stream>>>(rowptr, partial, nsb, N_NODES);
    scatter_store_xcd<<<1024, 256, 0, stream>>>(row, col, prank, rowptr, csr, N_EDGES);

    int gemm_grid = (N_NODES + 63) / 64;   // 782
    fc0_kernel<<<gemm_grid, 256, 0, stream>>>(x, fc0t, fc0_b, h16a, N_NODES);

    int eg_grid = (N_NODES + 127) / 128;   // 391
    f16* hcur = h16a;
    f16* hnext = h16b;
    for (int i = 0; i < L_LAYERS; i++) {
        layer_pre<<<SPMM_BLOCKS + CTX_BLOCKS, 256, 0, stream>>>(
            hcur, rowptr, csr, hi16,
            ctx_w + (size_t)i * H * K_EXP, ctx_b + (size_t)i * K_EXP, zbuf, N_NODES);
        expert_gemm<<<eg_grid, 256, 0, stream>>>(
            hi16, hcur, wfrag + (size_t)i * K_EXP * H * H, zbuf, hnext, N_NODES);
        f16* t = hcur; hcur = hnext; hnext = t;
    }
    fc1_kernel<<<gemm_grid, 256, 0, stream>>>(hcur, fc1t, fc1_b, out, N_NODES);
}

// Round 6
// 350.634 us; speedup vs baseline: 1.2158x; 1.0545x over previous
//
#include <hip/hip_runtime.h>

#define N_NODES 50000
#define N_EDGES 800000
#define DIN     128
#define H       96
#define K_EXP   8
#define L_LAYERS 4
#define C_OUT   40

typedef _Float16 f16;
typedef f16 f16x2 __attribute__((ext_vector_type(2)));
typedef f16 f16x4 __attribute__((ext_vector_type(4)));
typedef f16 f16x8 __attribute__((ext_vector_type(8)));
typedef float f32x4 __attribute__((ext_vector_type(4)));

// ---------------- CSR build + weight conversion (merged) ----------------

#define CONV_TOT (L_LAYERS * K_EXP * H * H)   // 294912
#define FC0_TOT  (DIN * H)                    // 12288
#define FC1_TOT  (48 * H)                     // 4608
#define CNT_BLOCKS ((N_EDGES + 255) / 256)            // 3125
#define CVT_BLOCKS ((CONV_TOT + FC0_TOT + FC1_TOT + 255) / 256)  // 1218

__global__ __launch_bounds__(256) void count_convert(const int* __restrict__ row,
                                                     int* __restrict__ deg,
                                                     int* __restrict__ p,
                                                     const float* __restrict__ conv_w,
                                                     const float* __restrict__ fc0_w,
                                                     const float* __restrict__ fc1_w,
                                                     f16* __restrict__ wfrag,
                                                     f16* __restrict__ fc0t,
                                                     f16* __restrict__ fc1t) {
    int tid = threadIdx.x;
    if ((int)blockIdx.x < CNT_BLOCKS) {
        int i = blockIdx.x * 256 + tid;
        if (i < N_EDGES) p[i] = atomicAdd(&deg[row[i]], 1);
    } else {
        int i = ((int)blockIdx.x - CNT_BLOCKS) * 256 + tid;
        if (i < CONV_TOT) {
            int o = i % H;
            int t = i / H;
            int d = t % H;
            int lk = t / H;
            int ct = o >> 4, lc = o & 15;
            int ks = d >> 5, quad = (d >> 3) & 3, j = d & 7;
            wfrag[(size_t)lk * 9216 + ct * 1536 + ks * 512 + (quad * 16 + lc) * 8 + j] =
                (f16)conv_w[i];
        } else if (i < CONV_TOT + FC0_TOT) {
            int j = i - CONV_TOT;      // j = d*96+o
            int o = j % H, d = j / H;
            fc0t[o * DIN + d] = (f16)fc0_w[j];
        } else if (i < CONV_TOT + FC0_TOT + FC1_TOT) {
            int j = i - CONV_TOT - FC0_TOT;  // target [o][d]
            int o = j / H, d = j % H;
            fc1t[j] = (o < C_OUT) ? (f16)fc1_w[d * C_OUT + o] : (f16)0.f;
        }
    }
}

__global__ __launch_bounds__(1024) void scanA(const int* __restrict__ deg,
                                              int* __restrict__ rowptr,
                                              int* __restrict__ partial, int n) {
    __shared__ int wsum[16];
    int tid  = threadIdx.x;
    int lane = tid & 63, wid = tid >> 6;
    int idx = blockIdx.x * 1024 + tid;
    int v = (idx < n) ? deg[idx] : 0;
    int s = v;
    #pragma unroll
    for (int off = 1; off < 64; off <<= 1) {
        int t = __shfl_up(s, off, 64);
        if (lane >= off) s += t;
    }
    if (lane == 63) wsum[wid] = s;
    __syncthreads();
    if (wid == 0 && lane < 16) {
        int w = wsum[lane];
        #pragma unroll
        for (int off = 1; off < 16; off <<= 1) {
            int t = __shfl_up(w, off, 16);
            if (lane >= off) w += t;
        }
        wsum[lane] = w;
    }
    __syncthreads();
    int waveoff = (wid == 0) ? 0 : wsum[wid - 1];
    if (idx < n) rowptr[idx + 1] = waveoff + s;
    if (tid == 1023) partial[blockIdx.x] = waveoff + s;
}

__global__ __launch_bounds__(1024) void scanC(int* __restrict__ rowptr,
                                              const int* __restrict__ partial,
                                              int nb, int n) {
    __shared__ int boff_s;
    int tid = threadIdx.x;
    if (tid < 64) {
        int v = 0;
        for (int j = tid; j < (int)blockIdx.x; j += 64) v += partial[j];
        #pragma unroll
        for (int off = 32; off >= 1; off >>= 1) v += __shfl_xor(v, off, 64);
        if (tid == 0) boff_s = v;
    }
    __syncthreads();
    int boff = boff_s;
    int idx = blockIdx.x * 1024 + tid;
    if (idx == 0) rowptr[0] = 0;
    if (idx < n) rowptr[idx + 1] += boff;
}

// ---------------- scatter (single pass) + fc0 MFMA, fused into one launch ----------------

#define SCT_BLOCKS 1024
#define FPAD 136

__global__ __launch_bounds__(256) void scatter_fc0(const int* __restrict__ row,
                                                   const int* __restrict__ col,
                                                   const int* __restrict__ p,
                                                   const int* __restrict__ rowptr,
                                                   int* __restrict__ csr,
                                                   const float* __restrict__ x,
                                                   const f16* __restrict__ fc0t,
                                                   const float* __restrict__ b,
                                                   f16* __restrict__ h16, int n) {
    __shared__ f16 As[64 * FPAD];
    __shared__ f16 Ws[96 * FPAD];
    int tid = threadIdx.x;
    if ((int)blockIdx.x < SCT_BLOCKS) {
        int stride = SCT_BLOCKS * 256;
        for (int i = blockIdx.x * 256 + tid; i < N_EDGES; i += stride)
            csr[rowptr[row[i]] + p[i]] = col[i];
        return;
    }
    int l = tid & 63, w = tid >> 6;
    int quad = l >> 4, lc = l & 15;
    int row0 = ((int)blockIdx.x - SCT_BLOCKS) * 64;

    for (int t = tid; t < 2048; t += 256) {
        int m = t >> 5, c4 = (t & 31) * 4;
        int gr = row0 + m;
        float4 v = {0.f, 0.f, 0.f, 0.f};
        if (gr < n) v = *(const float4*)(x + (size_t)gr * DIN + c4);
        f16x4 h4 = {(f16)v.x, (f16)v.y, (f16)v.z, (f16)v.w};
        *(f16x4*)&As[m * FPAD + c4] = h4;
    }
    for (int t = tid; t < 1536; t += 256) {
        int o = t >> 4, c8 = (t & 15) * 8;
        *(f16x8*)&Ws[o * FPAD + c8] = *(const f16x8*)(fc0t + o * DIN + c8);
    }
    __syncthreads();

    f16x8 afr[4];
    #pragma unroll
    for (int ks = 0; ks < 4; ks++)
        afr[ks] = *(const f16x8*)&As[(16 * w + lc) * FPAD + ks * 32 + quad * 8];

    f32x4 acc[6] = {};
    #pragma unroll
    for (int ct = 0; ct < 6; ct++) {
        #pragma unroll
        for (int ks = 0; ks < 4; ks++) {
            f16x8 bfr = *(const f16x8*)&Ws[(ct * 16 + lc) * FPAD + ks * 32 + quad * 8];
            acc[ct] = __builtin_amdgcn_mfma_f32_16x16x32_f16(afr[ks], bfr, acc[ct], 0, 0, 0);
        }
    }

    int m0 = 16 * w + quad * 4;
    #pragma unroll
    for (int r = 0; r < 4; r++) {
        int gr = row0 + m0 + r;
        if (gr < n) {
            #pragma unroll
            for (int ct = 0; ct < 6; ct++) {
                int o = ct * 16 + lc;
                h16[(size_t)gr * H + o] = (f16)fmaxf(acc[ct][r] + b[o], 0.f);
            }
        }
    }
}

// ---------------- fused per-layer pre-pass: spmm + ctx softmax ----------------
// spmm: 16 rows/block, one row per 16-lane group (3125 blocks, full occupancy).
// No cross-lane ops on the critical path: the group's column indices are
// group-uniform, every lane loads the index quad directly from csr (same 16B
// -> one coalesced L1-hot request). 8 independent gathers in flight per lane
// + next-quad index prefetch. Overread-safe: bytes past a row's csr range are
// later rows' indices or prank[] (all valid node ids), contribution masked.

#define SPMM_BLOCKS ((N_NODES + 15) / 16)    // 3125
#define CTX_BLOCKS  ((N_NODES + 255) / 256)  // 196

#define ACC8(v) { _Pragma("unroll") for (int q = 0; q < 8; q++) acc[q] += (float)(v)[q]; }

__global__ __launch_bounds__(256) void layer_pre(const f16* __restrict__ h16,
                                                 const int* __restrict__ rowptr,
                                                 const int* __restrict__ csr,
                                                 f16* __restrict__ hi16,
                                                 const float* __restrict__ cw,
                                                 const float* __restrict__ cb,
                                                 float* __restrict__ zt, int n) {
    __shared__ float ws[H * K_EXP];
    __shared__ float bs[K_EXP];
    int tid = threadIdx.x;
    if ((int)blockIdx.x < SPMM_BLOCKS) {
        int r  = blockIdx.x * 16 + (tid >> 4);
        int li = tid & 15;
        if (r >= n) return;
        bool act = li < 12;
        int j = rowptr[r], e = rowptr[r + 1];
        float acc[8] = {};
        const f16* hb = h16 + li * 8;

        int4 qa = *(const int4*)(csr + j);       // overread-safe
        int4 qb = *(const int4*)(csr + j + 4);

        while (j + 8 <= e) {
            int4 na = *(const int4*)(csr + j + 8);    // prefetch next iter
            int4 nb = *(const int4*)(csr + j + 12);
            f16x8 v0 = {}, v1 = {}, v2 = {}, v3 = {}, v4 = {}, v5 = {}, v6 = {}, v7 = {};
            if (act) {
                v0 = *(const f16x8*)(hb + (size_t)qa.x * H);
                v1 = *(const f16x8*)(hb + (size_t)qa.y * H);
                v2 = *(const f16x8*)(hb + (size_t)qa.z * H);
                v3 = *(const f16x8*)(hb + (size_t)qa.w * H);
                v4 = *(const f16x8*)(hb + (size_t)qb.x * H);
                v5 = *(const f16x8*)(hb + (size_t)qb.y * H);
                v6 = *(const f16x8*)(hb + (size_t)qb.z * H);
                v7 = *(const f16x8*)(hb + (size_t)qb.w * H);
            }
            ACC8(v0) ACC8(v1) ACC8(v2) ACC8(v3)
            ACC8(v4) ACC8(v5) ACC8(v6) ACC8(v7)
            j += 8; qa = na; qb = nb;
        }
        if (j + 4 <= e) {
            f16x8 v0 = {}, v1 = {}, v2 = {}, v3 = {};
            if (act) {
                v0 = *(const f16x8*)(hb + (size_t)qa.x * H);
                v1 = *(const f16x8*)(hb + (size_t)qa.y * H);
                v2 = *(const f16x8*)(hb + (size_t)qa.z * H);
                v3 = *(const f16x8*)(hb + (size_t)qa.w * H);
            }
            ACC8(v0) ACC8(v1) ACC8(v2) ACC8(v3)
            j += 4; qa = qb;
        }
        int rem = e - j;   // 0..3
        if (rem > 0) {
            f16x8 v0 = {}, v1 = {}, v2 = {};
            if (act) {
                v0 = *(const f16x8*)(hb + (size_t)qa.x * H);
                if (rem > 1) v1 = *(const f16x8*)(hb + (size_t)qa.y * H);
                if (rem > 2) v2 = *(const f16x8*)(hb + (size_t)qa.z * H);
            }
            ACC8(v0)
            if (rem > 1) ACC8(v1)
            if (rem > 2) ACC8(v2)
        }
        if (act) {
            f16x8 o;
            #pragma unroll
            for (int q = 0; q < 8; q++) o[q] = (f16)acc[q];
            *(f16x8*)(hi16 + (size_t)r * H + li * 8) = o;
        }
    } else {
        for (int t = tid; t < H * K_EXP; t += 256) ws[t] = cw[t];
        if (tid < K_EXP) bs[tid] = cb[tid];
        __syncthreads();
        int node = ((int)blockIdx.x - SPMM_BLOCKS) * 256 + tid;
        if (node >= n) return;
        float acc[K_EXP];
        #pragma unroll
        for (int k = 0; k < K_EXP; k++) acc[k] = bs[k];
        const f16* hr = h16 + (size_t)node * H;
        #pragma unroll 3
        for (int c8 = 0; c8 < 12; c8++) {
            f16x8 v = *(const f16x8*)(hr + c8 * 8);
            #pragma unroll
            for (int j = 0; j < 8; j++) {
                float hv = (float)v[j];
                int d = c8 * 8 + j;
                #pragma unroll
                for (int k = 0; k < K_EXP; k++) acc[k] += hv * ws[d * K_EXP + k];
            }
        }
        float mx = acc[0];
        #pragma unroll
        for (int k = 1; k < K_EXP; k++) mx = fmaxf(mx, acc[k]);
        float s = 0.f;
        #pragma unroll
        for (int k = 0; k < K_EXP; k++) { acc[k] = __expf(acc[k] - mx); s += acc[k]; }
        float inv = 1.f / s;
        // z stored [N][K] contiguous: two coalesced f32x4 stores
        f32x4 za = {acc[0] * inv, acc[1] * inv, acc[2] * inv, acc[3] * inv};
        f32x4 zb = {acc[4] * inv, acc[5] * inv, acc[6] * inv, acc[7] * inv};
        *(f32x4*)(zt + (size_t)node * K_EXP) = za;
        *(f32x4*)(zt + (size_t)node * K_EXP + 4) = zb;
    }
}

// ---------------- expert GEMM: z folded into A-operand, direct MFMA accumulation ----------------
// out[n] = sum_k z[n,k]*(hi[n] @ W_k) = sum_k (z[n,k]*hi[n]) @ W_k.
// A-frag rows map to lane&15, so the z scale is a per-lane f16 scalar per
// (Mtile, k): 3 packed f16x8 muls. All 24 MFMAs per ct accumulate directly
// into acc -- the f32 VALU combine and per-k tmp zero-init are gone.

#define EG_STAGE 2
#define EG_HALFS (EG_STAGE * 9216)   // 18432 halfs = 36 KB

__global__ __launch_bounds__(256) void expert_gemm(const f16* __restrict__ hi16,
                                                   const f16* __restrict__ hin16,
                                                   const f16* __restrict__ wfrag, // [K][9216]
                                                   const float* __restrict__ zt,  // [N][K]
                                                   f16* __restrict__ hout16, int n) {
    __shared__ f16 Wl[EG_HALFS];
    int tid = threadIdx.x;
    int l = tid & 63, w = tid >> 6;
    int quad = l >> 4, lc = l & 15;
    int brow = blockIdx.x * 128;
    int wrow0 = brow + w * 16;          // M-tile 0 row base
    int wrow1 = wrow0 + 64;             // M-tile 1 row base

    f16x8 afr0[3], afr1[3];
    #pragma unroll
    for (int ks = 0; ks < 3; ks++) {
        afr0[ks] = *(const f16x8*)(hi16 + (size_t)(wrow0 + lc) * H + ks * 32 + quad * 8);
        afr1[ks] = *(const f16x8*)(hi16 + (size_t)(wrow1 + lc) * H + ks * 32 + quad * 8);
    }

    // per-lane z rows (8 f32 each, contiguous), converted once to f16
    f32x4 z0a = *(const f32x4*)(zt + (size_t)(wrow0 + lc) * K_EXP);
    f32x4 z0b = *(const f32x4*)(zt + (size_t)(wrow0 + lc) * K_EXP + 4);
    f32x4 z1a = *(const f32x4*)(zt + (size_t)(wrow1 + lc) * K_EXP);
    f32x4 z1b = *(const f32x4*)(zt + (size_t)(wrow1 + lc) * K_EXP + 4);
    f16 zh0[K_EXP], zh1[K_EXP];
    #pragma unroll
    for (int k = 0; k < 4; k++) {
        zh0[k] = (f16)z0a[k]; zh0[k + 4] = (f16)z0b[k];
        zh1[k] = (f16)z1a[k]; zh1[k + 4] = (f16)z1b[k];
    }

    f32x4 acc0[6] = {};
    f32x4 acc1[6] = {};

    for (int kb = 0; kb < K_EXP; kb += EG_STAGE) {
        __syncthreads();
        const f16* src = wfrag + (size_t)kb * 9216;
        for (int t = tid; t < EG_HALFS / 8; t += 256)
            *(f16x8*)&Wl[t * 8] = *(const f16x8*)(src + t * 8);
        __syncthreads();

        #pragma unroll
        for (int k2 = 0; k2 < EG_STAGE; k2++) {
            int k = kb + k2;
            f16 s0 = zh0[k], s1 = zh1[k];
            f16x8 a0s[3], a1s[3];
            #pragma unroll
            for (int ks = 0; ks < 3; ks++) {
                a0s[ks] = afr0[ks] * s0;
                a1s[ks] = afr1[ks] * s1;
            }
            #pragma unroll
            for (int ct = 0; ct < 6; ct++) {
                f16x8 b0 = *(const f16x8*)&Wl[k2 * 9216 + ct * 1536 + 0 * 512 + l * 8];
                f16x8 b1 = *(const f16x8*)&Wl[k2 * 9216 + ct * 1536 + 1 * 512 + l * 8];
                f16x8 b2 = *(const f16x8*)&Wl[k2 * 9216 + ct * 1536 + 2 * 512 + l * 8];
                acc0[ct] = __builtin_amdgcn_mfma_f32_16x16x32_f16(a0s[0], b0, acc0[ct], 0, 0, 0);
                acc0[ct] = __builtin_amdgcn_mfma_f32_16x16x32_f16(a0s[1], b1, acc0[ct], 0, 0, 0);
                acc0[ct] = __builtin_amdgcn_mfma_f32_16x16x32_f16(a0s[2], b2, acc0[ct], 0, 0, 0);
                acc1[ct] = __builtin_amdgcn_mfma_f32_16x16x32_f16(a1s[0], b0, acc1[ct], 0, 0, 0);
                acc1[ct] = __builtin_amdgcn_mfma_f32_16x16x32_f16(a1s[1], b1, acc1[ct], 0, 0, 0);
                acc1[ct] = __builtin_amdgcn_mfma_f32_16x16x32_f16(a1s[2], b2, acc1[ct], 0, 0, 0);
            }
        }
    }

    #pragma unroll
    for (int r = 0; r < 4; r++) {
        int gr0 = wrow0 + quad * 4 + r;
        if (gr0 < n) {
            #pragma unroll
            for (int ct = 0; ct < 6; ct++) {
                int o = ct * 16 + lc;
                float v = fmaxf(acc0[ct][r] + (float)hin16[(size_t)gr0 * H + o], 0.f);
                hout16[(size_t)gr0 * H + o] = (f16)v;
            }
        }
        int gr1 = wrow1 + quad * 4 + r;
        if (gr1 < n) {
            #pragma unroll
            for (int ct = 0; ct < 6; ct++) {
                int o = ct * 16 + lc;
                float v = fmaxf(acc1[ct][r] + (float)hin16[(size_t)gr1 * H + o], 0.f);
                hout16[(size_t)gr1 * H + o] = (f16)v;
            }
        }
    }
}

// ---------------- fc1 via fp16 MFMA ----------------

#define APAD 104

__global__ __launch_bounds__(256) void fc1_kernel(const f16* __restrict__ h16,
                                                  const f16* __restrict__ fc1t,
                                                  const float* __restrict__ b,
                                                  float* __restrict__ out, int n) {
    __shared__ f16 As[64 * APAD];
    __shared__ f16 Ws[48 * APAD];
    int tid = threadIdx.x;
    int l = tid & 63, w = tid >> 6;
    int quad = l >> 4, lc = l & 15;
    int row0 = blockIdx.x * 64;

    for (int t = tid; t < 768; t += 256) {
        int m = t / 12, c8 = (t % 12) * 8;
        int gr = row0 + m;
        f16x8 v = {};
        if (gr < n) v = *(const f16x8*)(h16 + (size_t)gr * H + c8);
        *(f16x8*)&As[m * APAD + c8] = v;
    }
    for (int t = tid; t < 576; t += 256) {
        int o = t / 12, c8 = (t % 12) * 8;
        *(f16x8*)&Ws[o * APAD + c8] = *(const f16x8*)(fc1t + o * H + c8);
    }
    __syncthreads();

    f16x8 afr[3];
    #pragma unroll
    for (int ks = 0; ks < 3; ks++)
        afr[ks] = *(const f16x8*)&As[(16 * w + lc) * APAD + ks * 32 + quad * 8];

    f32x4 acc[3] = {};
    #pragma unroll
    for (int ct = 0; ct < 3; ct++) {
        #pragma unroll
        for (int ks = 0; ks < 3; ks++) {
            f16x8 bfr = *(const f16x8*)&Ws[(ct * 16 + lc) * APAD + ks * 32 + quad * 8];
            acc[ct] = __builtin_amdgcn_mfma_f32_16x16x32_f16(afr[ks], bfr, acc[ct], 0, 0, 0);
        }
    }

    int m0 = 16 * w + quad * 4;
    #pragma unroll
    for (int r = 0; r < 4; r++) {
        int gr = row0 + m0 + r;
        if (gr < n) {
            #pragma unroll
            for (int ct = 0; ct < 3; ct++) {
                int o = ct * 16 + lc;
                if (o < C_OUT)
                    out[(size_t)gr * C_OUT + o] = acc[ct][r] + b[o];
            }
        }
    }
}

// ---------------- launch ----------------

extern "C" void kernel_launch(void* const* d_in, const int* in_sizes, int n_in,
                              void* d_out, int out_size, void* d_ws, size_t ws_size,
                              hipStream_t stream) {
    const float* x      = (const float*)d_in[0];
    const int*   ei     = (const int*)d_in[1];
    const float* fc0_w  = (const float*)d_in[2];
    const float* fc0_b  = (const float*)d_in[3];
    const float* fc1_w  = (const float*)d_in[4];
    const float* fc1_b  = (const float*)d_in[5];
    const float* ctx_w  = (const float*)d_in[6];
    const float* ctx_b  = (const float*)d_in[7];
    const float* conv_w = (const float*)d_in[8];
    float* out = (float*)d_out;

    const size_t NH = (size_t)N_NODES * H;

    float* zbuf = (float*)d_ws;                          // [N][K]
    f16*   h16a = (f16*)(zbuf + (size_t)N_NODES * K_EXP);
    f16*   h16b = h16a + NH;
    f16*   hi16 = h16b + NH;
    f16*   wfrag= hi16 + NH;
    f16*   fc0t = wfrag + CONV_TOT;
    f16*   fc1t = fc0t + FC0_TOT;
    int* rowptr = (int*)(fc1t + FC1_TOT);                // N+1
    int* deg    = rowptr + (N_NODES + 1);                // N
    int* csr    = deg + N_NODES;                         // E
    int* prank  = csr + N_EDGES;                         // E  (also csr overread pad)
    int* partial  = prank + N_EDGES;                     // 64

    const int* row = ei;
    const int* col = ei + N_EDGES;

    hipMemsetAsync(deg, 0, sizeof(int) * N_NODES, stream);

    count_convert<<<CNT_BLOCKS + CVT_BLOCKS, 256, 0, stream>>>(
        row, deg, prank, conv_w, fc0_w, fc1_w, wfrag, fc0t, fc1t);
    int nsb = (N_NODES + 1023) / 1024;   // 49
    scanA<<<nsb, 1024, 0, stream>>>(deg, rowptr, partial, N_NODES);
    scanC<<<nsb, 1024, 0, stream>>>(rowptr, partial, nsb, N_NODES);

    int gemm_grid = (N_NODES + 63) / 64;   // 782
    scatter_fc0<<<SCT_BLOCKS + gemm_grid, 256, 0, stream>>>(
        row, col, prank, rowptr, csr, x, fc0t, fc0_b, h16a, N_NODES);

    int eg_grid = (N_NODES + 127) / 128;   // 391
    f16* hcur = h16a;
    f16* hnext = h16b;
    for (int i = 0; i < L_LAYERS; i++) {
        layer_pre<<<SPMM_BLOCKS + CTX_BLOCKS, 256, 0, stream>>>(
            hcur, rowptr, csr, hi16,
            ctx_w + (size_t)i * H * K_EXP, ctx_b + (size_t)i * K_EXP, zbuf, N_NODES);
        expert_gemm<<<eg_grid, 256, 0, stream>>>(
            hi16, hcur, wfrag + (size_t)i * K_EXP * H * H, zbuf, hnext, N_NODES);
        f16* t = hcur; hcur = hnext; hnext = t;
    }
    fc1_kernel<<<gemm_grid, 256, 0, stream>>>(hcur, fc1t, fc1_b, out, N_NODES);
}

// Round 7
// 336.757 us; speedup vs baseline: 1.2659x; 1.0412x over previous
//
#include <hip/hip_runtime.h>

#define N_NODES 50000
#define N_EDGES 800000
#define DIN     128
#define H       96
#define K_EXP   8
#define L_LAYERS 4
#define C_OUT   40

typedef _Float16 f16;
typedef f16 f16x2 __attribute__((ext_vector_type(2)));
typedef f16 f16x4 __attribute__((ext_vector_type(4)));
typedef f16 f16x8 __attribute__((ext_vector_type(8)));
typedef float f32x4 __attribute__((ext_vector_type(4)));

// ---------------- CSR build + weight conversion (merged) ----------------

#define CONV_TOT (L_LAYERS * K_EXP * H * H)   // 294912
#define FC0_TOT  (DIN * H)                    // 12288
#define FC1_TOT  (48 * H)                     // 4608
#define CNT_BLOCKS ((N_EDGES + 255) / 256)            // 3125
#define CVT_BLOCKS ((CONV_TOT + FC0_TOT + FC1_TOT + 255) / 256)  // 1218

__global__ __launch_bounds__(256) void count_convert(const int* __restrict__ row,
                                                     int* __restrict__ deg,
                                                     int* __restrict__ p,
                                                     const float* __restrict__ conv_w,
                                                     const float* __restrict__ fc0_w,
                                                     const float* __restrict__ fc1_w,
                                                     f16* __restrict__ wfrag,
                                                     f16* __restrict__ fc0t,
                                                     f16* __restrict__ fc1t) {
    int tid = threadIdx.x;
    if ((int)blockIdx.x < CNT_BLOCKS) {
        int i = blockIdx.x * 256 + tid;
        if (i < N_EDGES) p[i] = atomicAdd(&deg[row[i]], 1);
    } else {
        int i = ((int)blockIdx.x - CNT_BLOCKS) * 256 + tid;
        if (i < CONV_TOT) {
            int o = i % H;
            int t = i / H;
            int d = t % H;
            int lk = t / H;
            int ct = o >> 4, lc = o & 15;
            int ks = d >> 5, quad = (d >> 3) & 3, j = d & 7;
            wfrag[(size_t)lk * 9216 + ct * 1536 + ks * 512 + (quad * 16 + lc) * 8 + j] =
                (f16)conv_w[i];
        } else if (i < CONV_TOT + FC0_TOT) {
            int j = i - CONV_TOT;      // j = d*96+o
            int o = j % H, d = j / H;
            fc0t[o * DIN + d] = (f16)fc0_w[j];
        } else if (i < CONV_TOT + FC0_TOT + FC1_TOT) {
            int j = i - CONV_TOT - FC0_TOT;  // target [o][d]
            int o = j / H, d = j % H;
            fc1t[j] = (o < C_OUT) ? (f16)fc1_w[d * C_OUT + o] : (f16)0.f;
        }
    }
}

__global__ __launch_bounds__(1024) void scanA(const int* __restrict__ deg,
                                              int* __restrict__ rowptr,
                                              int* __restrict__ partial, int n) {
    __shared__ int wsum[16];
    int tid  = threadIdx.x;
    int lane = tid & 63, wid = tid >> 6;
    int idx = blockIdx.x * 1024 + tid;
    int v = (idx < n) ? deg[idx] : 0;
    int s = v;
    #pragma unroll
    for (int off = 1; off < 64; off <<= 1) {
        int t = __shfl_up(s, off, 64);
        if (lane >= off) s += t;
    }
    if (lane == 63) wsum[wid] = s;
    __syncthreads();
    if (wid == 0 && lane < 16) {
        int w = wsum[lane];
        #pragma unroll
        for (int off = 1; off < 16; off <<= 1) {
            int t = __shfl_up(w, off, 16);
            if (lane >= off) w += t;
        }
        wsum[lane] = w;
    }
    __syncthreads();
    int waveoff = (wid == 0) ? 0 : wsum[wid - 1];
    if (idx < n) rowptr[idx + 1] = waveoff + s;
    if (tid == 1023) partial[blockIdx.x] = waveoff + s;
}

__global__ __launch_bounds__(1024) void scanC(int* __restrict__ rowptr,
                                              const int* __restrict__ partial,
                                              int nb, int n) {
    __shared__ int boff_s;
    int tid = threadIdx.x;
    if (tid < 64) {
        int v = 0;
        for (int j = tid; j < (int)blockIdx.x; j += 64) v += partial[j];
        #pragma unroll
        for (int off = 32; off >= 1; off >>= 1) v += __shfl_xor(v, off, 64);
        if (tid == 0) boff_s = v;
    }
    __syncthreads();
    int boff = boff_s;
    int idx = blockIdx.x * 1024 + tid;
    if (idx == 0) rowptr[0] = 0;
    if (idx < n) rowptr[idx + 1] += boff;
}

// ---------------- scatter (single pass) + fc0 MFMA, fused into one launch ----------------

#define SCT_BLOCKS 1024
#define FPAD 136

__global__ __launch_bounds__(256) void scatter_fc0(const int* __restrict__ row,
                                                   const int* __restrict__ col,
                                                   const int* __restrict__ p,
                                                   const int* __restrict__ rowptr,
                                                   int* __restrict__ csr,
                                                   const float* __restrict__ x,
                                                   const f16* __restrict__ fc0t,
                                                   const float* __restrict__ b,
                                                   f16* __restrict__ h16, int n) {
    __shared__ f16 As[64 * FPAD];
    __shared__ f16 Ws[96 * FPAD];
    int tid = threadIdx.x;
    if ((int)blockIdx.x < SCT_BLOCKS) {
        int stride = SCT_BLOCKS * 256;
        for (int i = blockIdx.x * 256 + tid; i < N_EDGES; i += stride)
            csr[rowptr[row[i]] + p[i]] = col[i];
        return;
    }
    int l = tid & 63, w = tid >> 6;
    int quad = l >> 4, lc = l & 15;
    int row0 = ((int)blockIdx.x - SCT_BLOCKS) * 64;

    for (int t = tid; t < 2048; t += 256) {
        int m = t >> 5, c4 = (t & 31) * 4;
        int gr = row0 + m;
        float4 v = {0.f, 0.f, 0.f, 0.f};
        if (gr < n) v = *(const float4*)(x + (size_t)gr * DIN + c4);
        f16x4 h4 = {(f16)v.x, (f16)v.y, (f16)v.z, (f16)v.w};
        *(f16x4*)&As[m * FPAD + c4] = h4;
    }
    for (int t = tid; t < 1536; t += 256) {
        int o = t >> 4, c8 = (t & 15) * 8;
        *(f16x8*)&Ws[o * FPAD + c8] = *(const f16x8*)(fc0t + o * DIN + c8);
    }
    __syncthreads();

    f16x8 afr[4];
    #pragma unroll
    for (int ks = 0; ks < 4; ks++)
        afr[ks] = *(const f16x8*)&As[(16 * w + lc) * FPAD + ks * 32 + quad * 8];

    f32x4 acc[6] = {};
    #pragma unroll
    for (int ct = 0; ct < 6; ct++) {
        #pragma unroll
        for (int ks = 0; ks < 4; ks++) {
            f16x8 bfr = *(const f16x8*)&Ws[(ct * 16 + lc) * FPAD + ks * 32 + quad * 8];
            acc[ct] = __builtin_amdgcn_mfma_f32_16x16x32_f16(afr[ks], bfr, acc[ct], 0, 0, 0);
        }
    }

    int m0 = 16 * w + quad * 4;
    #pragma unroll
    for (int r = 0; r < 4; r++) {
        int gr = row0 + m0 + r;
        if (gr < n) {
            #pragma unroll
            for (int ct = 0; ct < 6; ct++) {
                int o = ct * 16 + lc;
                h16[(size_t)gr * H + o] = (f16)fmaxf(acc[ct][r] + b[o], 0.f);
            }
        }
    }
}

// ---------------- fully fused layer: spmm + ctx softmax + expert GEMM ----------------
// One block = 64 rows. Phase 1: spmm gather for own rows -> hi in LDS (row-
// local dependency). Phase 2: ctx softmax for own rows -> z (f16) in LDS.
// Phase 3: expert GEMM, A = z-scaled hi fragments from LDS, W staged one
// expert at a time (18 KB), residual + relu, store hnext. hi and z never
// touch global memory; one launch per layer instead of two.
// hi rows padded to 104 halfs -> worst 2-way LDS bank aliasing (free).
// csr overread-safe as before (prank[] follows csr, all valid node ids).

#define LF_ROWS   64
#define LF_BLOCKS ((N_NODES + LF_ROWS - 1) / LF_ROWS)   // 782
#define HPAD      104

#define ACC8(v) { _Pragma("unroll") for (int q = 0; q < 8; q++) acc[q] += (float)(v)[q]; }

__global__ __launch_bounds__(256, 4) void layer_fused(const f16* __restrict__ h16,
                                                      const int* __restrict__ rowptr,
                                                      const int* __restrict__ csr,
                                                      const float* __restrict__ cw,
                                                      const float* __restrict__ cb,
                                                      const f16* __restrict__ wfrag, // [K][9216]
                                                      f16* __restrict__ hout16, int n) {
    __shared__ f16 hi_lds[LF_ROWS * HPAD];   // 13.3 KB
    __shared__ f16 Wl[9216];                 // 18 KB
    __shared__ float ws[H * K_EXP];          // 3 KB
    __shared__ f16 z_lds[LF_ROWS * K_EXP];   // 1 KB
    __shared__ float bs[K_EXP];

    int tid = threadIdx.x;
    int brow = blockIdx.x * LF_ROWS;

    // stage ctx weights (visible to ctx phase after first barrier)
    for (int t = tid; t < H * K_EXP; t += 256) ws[t] = cw[t];
    if (tid < K_EXP) bs[tid] = cb[tid];

    // ---- phase 1: spmm for own 64 rows (group g -> rows brow+g*4..+3)
    {
        int g = tid >> 4, li = tid & 15;
        bool act = li < 12;
        const f16* hb = h16 + li * 8;
        for (int sub = 0; sub < 4; sub++) {
            int r = brow + g * 4 + sub;
            if (r >= n) break;
            int j = rowptr[r], e = rowptr[r + 1];
            float acc[8] = {};
            int4 qa = *(const int4*)(csr + j);       // overread-safe
            int4 qb = *(const int4*)(csr + j + 4);
            while (j + 8 <= e) {
                int4 na = *(const int4*)(csr + j + 8);
                int4 nb = *(const int4*)(csr + j + 12);
                f16x8 v0 = {}, v1 = {}, v2 = {}, v3 = {}, v4 = {}, v5 = {}, v6 = {}, v7 = {};
                if (act) {
                    v0 = *(const f16x8*)(hb + (size_t)qa.x * H);
                    v1 = *(const f16x8*)(hb + (size_t)qa.y * H);
                    v2 = *(const f16x8*)(hb + (size_t)qa.z * H);
                    v3 = *(const f16x8*)(hb + (size_t)qa.w * H);
                    v4 = *(const f16x8*)(hb + (size_t)qb.x * H);
                    v5 = *(const f16x8*)(hb + (size_t)qb.y * H);
                    v6 = *(const f16x8*)(hb + (size_t)qb.z * H);
                    v7 = *(const f16x8*)(hb + (size_t)qb.w * H);
                }
                ACC8(v0) ACC8(v1) ACC8(v2) ACC8(v3)
                ACC8(v4) ACC8(v5) ACC8(v6) ACC8(v7)
                j += 8; qa = na; qb = nb;
            }
            if (j + 4 <= e) {
                f16x8 v0 = {}, v1 = {}, v2 = {}, v3 = {};
                if (act) {
                    v0 = *(const f16x8*)(hb + (size_t)qa.x * H);
                    v1 = *(const f16x8*)(hb + (size_t)qa.y * H);
                    v2 = *(const f16x8*)(hb + (size_t)qa.z * H);
                    v3 = *(const f16x8*)(hb + (size_t)qa.w * H);
                }
                ACC8(v0) ACC8(v1) ACC8(v2) ACC8(v3)
                j += 4; qa = qb;
            }
            int rem = e - j;   // 0..3
            if (rem > 0) {
                f16x8 v0 = {}, v1 = {}, v2 = {};
                if (act) {
                    v0 = *(const f16x8*)(hb + (size_t)qa.x * H);
                    if (rem > 1) v1 = *(const f16x8*)(hb + (size_t)qa.y * H);
                    if (rem > 2) v2 = *(const f16x8*)(hb + (size_t)qa.z * H);
                }
                ACC8(v0)
                if (rem > 1) ACC8(v1)
                if (rem > 2) ACC8(v2)
            }
            if (act) {
                f16x8 o;
                #pragma unroll
                for (int q = 0; q < 8; q++) o[q] = (f16)acc[q];
                *(f16x8*)&hi_lds[(g * 4 + sub) * HPAD + li * 8] = o;
            }
        }
    }

    // ---- phase 2: ctx softmax for own rows (thread t -> node brow+t)
    // (ws/bs visibility: staged above, consumed after the barrier below by
    //  the GEMM phase? No -- ctx reads ws BEFORE a barrier. The staging loop
    //  ran in program order on the same wave for low tids; cross-wave safety
    //  requires a barrier first.)
    __syncthreads();   // ws, bs ready (and hi/z writers done later anyway)
    if (tid < LF_ROWS) {
        int node = brow + tid;
        if (node < n) {
            float acc[K_EXP];
            #pragma unroll
            for (int k = 0; k < K_EXP; k++) acc[k] = bs[k];
            const f16* hr = h16 + (size_t)node * H;
            #pragma unroll 3
            for (int c8 = 0; c8 < 12; c8++) {
                f16x8 v = *(const f16x8*)(hr + c8 * 8);
                #pragma unroll
                for (int j = 0; j < 8; j++) {
                    float hv = (float)v[j];
                    int d = c8 * 8 + j;
                    #pragma unroll
                    for (int k = 0; k < K_EXP; k++) acc[k] += hv * ws[d * K_EXP + k];
                }
            }
            float mx = acc[0];
            #pragma unroll
            for (int k = 1; k < K_EXP; k++) mx = fmaxf(mx, acc[k]);
            float s = 0.f;
            #pragma unroll
            for (int k = 0; k < K_EXP; k++) { acc[k] = __expf(acc[k] - mx); s += acc[k]; }
            float inv = 1.f / s;
            f16x8 zo;
            #pragma unroll
            for (int k = 0; k < K_EXP; k++) zo[k] = (f16)(acc[k] * inv);
            *(f16x8*)&z_lds[tid * K_EXP] = zo;
        }
    }
    __syncthreads();   // hi_lds + z_lds ready

    // ---- phase 3: expert GEMM (wave w -> rows brow+w*16 .. +15)
    int l = tid & 63, w = tid >> 6;
    int quad = l >> 4, lc = l & 15;

    f16x8 afr[3];
    #pragma unroll
    for (int ks = 0; ks < 3; ks++)
        afr[ks] = *(const f16x8*)&hi_lds[(w * 16 + lc) * HPAD + ks * 32 + quad * 8];
    f16x8 zh = *(const f16x8*)&z_lds[(w * 16 + lc) * K_EXP];

    f32x4 acc[6] = {};
    for (int k = 0; k < K_EXP; k++) {
        if (k) __syncthreads();          // prior compute done reading Wl
        const f16* src = wfrag + (size_t)k * 9216;
        for (int t = tid; t < 1152; t += 256)
            *(f16x8*)&Wl[t * 8] = *(const f16x8*)(src + t * 8);
        __syncthreads();

        f16 s = zh[k];
        f16x8 as0 = afr[0] * s, as1 = afr[1] * s, as2 = afr[2] * s;
        #pragma unroll
        for (int ct = 0; ct < 6; ct++) {
            f16x8 b0 = *(const f16x8*)&Wl[ct * 1536 + 0 * 512 + l * 8];
            f16x8 b1 = *(const f16x8*)&Wl[ct * 1536 + 1 * 512 + l * 8];
            f16x8 b2 = *(const f16x8*)&Wl[ct * 1536 + 2 * 512 + l * 8];
            acc[ct] = __builtin_amdgcn_mfma_f32_16x16x32_f16(as0, b0, acc[ct], 0, 0, 0);
            acc[ct] = __builtin_amdgcn_mfma_f32_16x16x32_f16(as1, b1, acc[ct], 0, 0, 0);
            acc[ct] = __builtin_amdgcn_mfma_f32_16x16x32_f16(as2, b2, acc[ct], 0, 0, 0);
        }
    }

    #pragma unroll
    for (int r = 0; r < 4; r++) {
        int gr = brow + w * 16 + quad * 4 + r;
        if (gr < n) {
            #pragma unroll
            for (int ct = 0; ct < 6; ct++) {
                int o = ct * 16 + lc;
                float v = fmaxf(acc[ct][r] + (float)h16[(size_t)gr * H + o], 0.f);
                hout16[(size_t)gr * H + o] = (f16)v;
            }
        }
    }
}

// ---------------- fc1 via fp16 MFMA ----------------

#define APAD 104

__global__ __launch_bounds__(256) void fc1_kernel(const f16* __restrict__ h16,
                                                  const f16* __restrict__ fc1t,
                                                  const float* __restrict__ b,
                                                  float* __restrict__ out, int n) {
    __shared__ f16 As[64 * APAD];
    __shared__ f16 Ws[48 * APAD];
    int tid = threadIdx.x;
    int l = tid & 63, w = tid >> 6;
    int quad = l >> 4, lc = l & 15;
    int row0 = blockIdx.x * 64;

    for (int t = tid; t < 768; t += 256) {
        int m = t / 12, c8 = (t % 12) * 8;
        int gr = row0 + m;
        f16x8 v = {};
        if (gr < n) v = *(const f16x8*)(h16 + (size_t)gr * H + c8);
        *(f16x8*)&As[m * APAD + c8] = v;
    }
    for (int t = tid; t < 576; t += 256) {
        int o = t / 12, c8 = (t % 12) * 8;
        *(f16x8*)&Ws[o * APAD + c8] = *(const f16x8*)(fc1t + o * H + c8);
    }
    __syncthreads();

    f16x8 afr[3];
    #pragma unroll
    for (int ks = 0; ks < 3; ks++)
        afr[ks] = *(const f16x8*)&As[(16 * w + lc) * APAD + ks * 32 + quad * 8];

    f32x4 acc[3] = {};
    #pragma unroll
    for (int ct = 0; ct < 3; ct++) {
        #pragma unroll
        for (int ks = 0; ks < 3; ks++) {
            f16x8 bfr = *(const f16x8*)&Ws[(ct * 16 + lc) * APAD + ks * 32 + quad * 8];
            acc[ct] = __builtin_amdgcn_mfma_f32_16x16x32_f16(afr[ks], bfr, acc[ct], 0, 0, 0);
        }
    }

    int m0 = 16 * w + quad * 4;
    #pragma unroll
    for (int r = 0; r < 4; r++) {
        int gr = row0 + m0 + r;
        if (gr < n) {
            #pragma unroll
            for (int ct = 0; ct < 3; ct++) {
                int o = ct * 16 + lc;
                if (o < C_OUT)
                    out[(size_t)gr * C_OUT + o] = acc[ct][r] + b[o];
            }
        }
    }
}

// ---------------- launch ----------------

extern "C" void kernel_launch(void* const* d_in, const int* in_sizes, int n_in,
                              void* d_out, int out_size, void* d_ws, size_t ws_size,
                              hipStream_t stream) {
    const float* x      = (const float*)d_in[0];
    const int*   ei     = (const int*)d_in[1];
    const float* fc0_w  = (const float*)d_in[2];
    const float* fc0_b  = (const float*)d_in[3];
    const float* fc1_w  = (const float*)d_in[4];
    const float* fc1_b  = (const float*)d_in[5];
    const float* ctx_w  = (const float*)d_in[6];
    const float* ctx_b  = (const float*)d_in[7];
    const float* conv_w = (const float*)d_in[8];
    float* out = (float*)d_out;

    const size_t NH = (size_t)N_NODES * H;

    f16*   h16a = (f16*)d_ws;
    f16*   h16b = h16a + NH;
    f16*   wfrag= h16b + NH;
    f16*   fc0t = wfrag + CONV_TOT;
    f16*   fc1t = fc0t + FC0_TOT;
    int* rowptr = (int*)(fc1t + FC1_TOT);                // N+1
    int* deg    = rowptr + (N_NODES + 1);                // N
    int* csr    = deg + N_NODES;                         // E
    int* prank  = csr + N_EDGES;                         // E  (also csr overread pad)
    int* partial  = prank + N_EDGES;                     // 64

    const int* row = ei;
    const int* col = ei + N_EDGES;

    hipMemsetAsync(deg, 0, sizeof(int) * N_NODES, stream);

    count_convert<<<CNT_BLOCKS + CVT_BLOCKS, 256, 0, stream>>>(
        row, deg, prank, conv_w, fc0_w, fc1_w, wfrag, fc0t, fc1t);
    int nsb = (N_NODES + 1023) / 1024;   // 49
    scanA<<<nsb, 1024, 0, stream>>>(deg, rowptr, partial, N_NODES);
    scanC<<<nsb, 1024, 0, stream>>>(rowptr, partial, nsb, N_NODES);

    int gemm_grid = (N_NODES + 63) / 64;   // 782
    scatter_fc0<<<SCT_BLOCKS + gemm_grid, 256, 0, stream>>>(
        row, col, prank, rowptr, csr, x, fc0t, fc0_b, h16a, N_NODES);

    f16* hcur = h16a;
    f16* hnext = h16b;
    for (int i = 0; i < L_LAYERS; i++) {
        layer_fused<<<LF_BLOCKS, 256, 0, stream>>>(
            hcur, rowptr, csr,
            ctx_w + (size_t)i * H * K_EXP, ctx_b + (size_t)i * K_EXP,
            wfrag + (size_t)i * K_EXP * H * H, hnext, N_NODES);
        f16* t = hcur; hcur = hnext; hnext = t;
    }
    fc1_kernel<<<gemm_grid, 256, 0, stream>>>(hcur, fc1t, fc1_b, out, N_NODES);
}